// Round 2
// baseline (3989.743 us; speedup 1.0000x reference)
//
#include <hip/hip_runtime.h>
#include <hip/hip_bf16.h>

typedef __hip_bfloat16 bf16;

// ---------------------------------------------------------------------------
// Problem constants: B=2, L=2048, D=1024, H=4*D=4096, HEADS=16, dh=64
// Inputs/outputs are fp32 (reference dtype); intermediates bf16 in ws.
// ---------------------------------------------------------------------------
#define CB 2
#define CL 2048
#define CD 1024
#define CH 4096
#define NHEADS 16
#define DH 64

__device__ __forceinline__ float ldf(const float* p, size_t i) { return p[i]; }
__device__ __forceinline__ float ldf(const bf16* p, size_t i) { return __bfloat162float(p[i]); }
__device__ __forceinline__ void stf(float* p, size_t i, float v) { p[i] = v; }
__device__ __forceinline__ void stf(bf16* p, size_t i, float v) { p[i] = __float2bfloat16(v); }

__global__ void zero_stats_kernel(float* s) {
    if (threadIdx.x < 16) s[threadIdx.x] = 0.0f;
}

// ---------------------------------------------------------------------------
// Tiled GEMM: C[M,N] = A[M,K] @ W[K,N] + bias[N], optional ReLU.
// A: fp32 or bf16; W/bias fp32 (problem inputs); C bf16 (ws intermediate).
// BM=BN=64, BK=32, 256 threads, 4x4 microtile, fp32 accumulate.
// ---------------------------------------------------------------------------
template <typename TA>
__global__ void gemm_bias(const TA* __restrict__ A,
                          const float* __restrict__ W,
                          const float* __restrict__ bias,
                          bf16* __restrict__ C,
                          int M, int N, int K, int relu)
{
    __shared__ float As[64][36];   // pad: 2-way conflicts only (free)
    __shared__ float Bs[32][68];

    const int tid = threadIdx.x;           // 256
    const int tx = tid & 15, ty = tid >> 4;
    const int row0 = blockIdx.y * 64;
    const int col0 = blockIdx.x * 64;

    float acc[4][4] = {};

    for (int k0 = 0; k0 < K; k0 += 32) {
        #pragma unroll
        for (int i = tid; i < 64 * 32; i += 256) {
            int m = i >> 5, kk = i & 31;
            As[m][kk] = ldf(A, (size_t)(row0 + m) * K + k0 + kk);
        }
        #pragma unroll
        for (int i = tid; i < 32 * 64; i += 256) {
            int kk = i >> 6, n = i & 63;
            Bs[kk][n] = W[(size_t)(k0 + kk) * N + col0 + n];
        }
        __syncthreads();

        #pragma unroll
        for (int kk = 0; kk < 32; ++kk) {
            float a[4], b[4];
            #pragma unroll
            for (int i = 0; i < 4; ++i) a[i] = As[ty * 4 + i][kk];
            #pragma unroll
            for (int j = 0; j < 4; ++j) b[j] = Bs[kk][tx * 4 + j];
            #pragma unroll
            for (int i = 0; i < 4; ++i)
                #pragma unroll
                for (int j = 0; j < 4; ++j)
                    acc[i][j] += a[i] * b[j];
        }
        __syncthreads();
    }

    #pragma unroll
    for (int i = 0; i < 4; ++i) {
        int m = row0 + ty * 4 + i;
        #pragma unroll
        for (int j = 0; j < 4; ++j) {
            int n = col0 + tx * 4 + j;
            float v = acc[i][j] + bias[n];
            if (relu) v = fmaxf(v, 0.0f);
            C[(size_t)m * N + n] = __float2bfloat16(v);
        }
    }
}

// ---------------------------------------------------------------------------
// Attention: per block = 4 query rows of one (batch, head).
// Full score row (2048) in LDS; wave-per-row softmax; tiled PV.
// Q/K/V layout: [B*L, D] bf16, head h at columns h*64 .. h*64+63.
// ---------------------------------------------------------------------------
__global__ void attn_kernel(const bf16* __restrict__ Q,
                            const bf16* __restrict__ K,
                            const bf16* __restrict__ V,
                            bf16* __restrict__ O)
{
    __shared__ float S[4][CL];       // 32 KB
    __shared__ float Qs[4][DH];      //  1 KB
    __shared__ float Ts[64][DH + 1]; // 16.25 KB

    const int tid = threadIdx.x;     // 256
    const int q0 = blockIdx.x * 4;
    const int h  = blockIdx.y;
    const int b  = blockIdx.z;
    const size_t base = (size_t)b * CL * CD + (size_t)h * DH;

    for (int i = tid; i < 4 * DH; i += 256) {
        int r = i >> 6, d = i & 63;
        Qs[r][d] = __bfloat162float(Q[base + (size_t)(q0 + r) * CD + d]);
    }

    const int r    = tid >> 6;   // one wave per query row
    const int lane = tid & 63;
    const float scale = 0.125f;  // 1/sqrt(64)

    for (int t0 = 0; t0 < CL; t0 += 64) {
        for (int i = tid; i < 64 * DH; i += 256) {
            int kr = i >> 6, d = i & 63;
            Ts[kr][d] = __bfloat162float(K[base + (size_t)(t0 + kr) * CD + d]);
        }
        __syncthreads();
        float acc = 0.0f;
        #pragma unroll 8
        for (int d = 0; d < DH; ++d) acc += Qs[r][d] * Ts[lane][d];
        S[r][t0 + lane] = acc * scale;
        __syncthreads();
    }

    float mx = -1e30f;
    for (int i = lane; i < CL; i += 64) mx = fmaxf(mx, S[r][i]);
    #pragma unroll
    for (int off = 32; off; off >>= 1) mx = fmaxf(mx, __shfl_xor(mx, off, 64));
    float l = 0.0f;
    for (int i = lane; i < CL; i += 64) {
        float e = __expf(S[r][i] - mx);
        S[r][i] = e;
        l += e;
    }
    #pragma unroll
    for (int off = 32; off; off >>= 1) l += __shfl_xor(l, off, 64);
    const float inv = 1.0f / l;
    __syncthreads();

    float o = 0.0f;
    for (int t0 = 0; t0 < CL; t0 += 64) {
        for (int i = tid; i < 64 * DH; i += 256) {
            int vr = i >> 6, d = i & 63;
            Ts[vr][d] = __bfloat162float(V[base + (size_t)(t0 + vr) * CD + d]);
        }
        __syncthreads();
        #pragma unroll 8
        for (int j = 0; j < 64; ++j) o += S[r][t0 + j] * Ts[j][lane];
        __syncthreads();
    }
    O[base + (size_t)(q0 + r) * CD + lane] = __float2bfloat16(o * inv);
}

// ---------------------------------------------------------------------------
// Joint-(L,C) LayerNorm per batch sample, two-pass.
// ---------------------------------------------------------------------------
template <typename TA, typename TB>
__global__ void ln_reduce(const TA* __restrict__ a,
                          const TB* __restrict__ b,
                          float* __restrict__ stats, int perBatch)
{
    const int bId = blockIdx.y;
    const size_t base = (size_t)bId * perBatch;
    const int tid = threadIdx.x;
    float s1 = 0.0f, s2 = 0.0f;
    for (int i = blockIdx.x * 256 + tid; i < perBatch; i += gridDim.x * 256) {
        float v = ldf(a, base + i) + ldf(b, base + i);
        s1 += v;
        s2 += v * v;
    }
    #pragma unroll
    for (int off = 32; off; off >>= 1) {
        s1 += __shfl_xor(s1, off, 64);
        s2 += __shfl_xor(s2, off, 64);
    }
    __shared__ float r1[4], r2[4];
    const int w = tid >> 6, lane = tid & 63;
    if (lane == 0) { r1[w] = s1; r2[w] = s2; }
    __syncthreads();
    if (tid == 0) {
        atomicAdd(&stats[bId * 2 + 0], r1[0] + r1[1] + r1[2] + r1[3]);
        atomicAdd(&stats[bId * 2 + 1], r2[0] + r2[1] + r2[2] + r2[3]);
    }
}

template <typename TA, typename TB, typename TO>
__global__ void ln_apply(const TA* __restrict__ a,
                         const TB* __restrict__ b,
                         const float* __restrict__ stats,
                         TO* __restrict__ out, int perBatch)
{
    const int bId = blockIdx.y;
    const size_t base = (size_t)bId * perBatch;
    const float n = (float)perBatch;
    const float mean = stats[bId * 2 + 0] / n;
    const float var  = stats[bId * 2 + 1] / n - mean * mean + 1e-5f;
    const float inv  = rsqrtf(var);
    for (int i = blockIdx.x * 256 + threadIdx.x; i < perBatch; i += gridDim.x * 256) {
        float v = ldf(a, base + i) + ldf(b, base + i);
        stf(out, base + i, (v - mean) * inv);
    }
}

// ---------------------------------------------------------------------------
extern "C" void kernel_launch(void* const* d_in, const int* in_sizes, int n_in,
                              void* d_out, int out_size, void* d_ws, size_t ws_size,
                              hipStream_t stream)
{
    const float* x  = (const float*)d_in[0];
    const float* wq = (const float*)d_in[1];
    const float* bq = (const float*)d_in[2];
    const float* wk = (const float*)d_in[3];
    const float* bk = (const float*)d_in[4];
    const float* wv = (const float*)d_in[5];
    const float* bv = (const float*)d_in[6];
    const float* w1 = (const float*)d_in[7];
    const float* b1 = (const float*)d_in[8];
    const float* w2 = (const float*)d_in[9];
    const float* b2 = (const float*)d_in[10];

    const int BL = CB * CL;          // 4096 rows
    const int perBatch = CL * CD;    // 2M elements per batch sample

    // ws layout (bf16 intermediates): peak 48 MB + 64 B
    //   [0,32MB):  q|k|v|attn  -> reused as ff1 (32MB) after LN1
    //   [32,40MB): hbuf
    //   [40,48MB): ff2
    //   [48MB):    stats (16 floats)
    char* ws = (char*)d_ws;
    const size_t SZ_BLD = (size_t)BL * CD * sizeof(bf16);   // 8 MB
    bf16* q    = (bf16*)(ws);
    bf16* kT   = (bf16*)(ws + SZ_BLD);
    bf16* v    = (bf16*)(ws + 2 * SZ_BLD);
    bf16* attn = (bf16*)(ws + 3 * SZ_BLD);
    bf16* ff1  = (bf16*)(ws);                // reuse q..attn region (32 MB)
    bf16* hbuf = (bf16*)(ws + 4 * SZ_BLD);
    bf16* ff2  = (bf16*)(ws + 5 * SZ_BLD);
    float* stats = (float*)(ws + 6 * SZ_BLD);

    dim3 blk(256);

    zero_stats_kernel<<<1, 64, 0, stream>>>(stats);

    // QKV projections (A = x fp32)
    gemm_bias<float><<<dim3(CD / 64, BL / 64), blk, 0, stream>>>(x, wq, bq, q,  BL, CD, CD, 0);
    gemm_bias<float><<<dim3(CD / 64, BL / 64), blk, 0, stream>>>(x, wk, bk, kT, BL, CD, CD, 0);
    gemm_bias<float><<<dim3(CD / 64, BL / 64), blk, 0, stream>>>(x, wv, bv, v,  BL, CD, CD, 0);

    // multi-head attention
    attn_kernel<<<dim3(CL / 4, NHEADS, CB), blk, 0, stream>>>(q, kT, v, attn);

    // residual + joint-(L,C) LayerNorm -> h
    ln_reduce<float, bf16><<<dim3(256, CB), blk, 0, stream>>>(x, attn, stats, perBatch);
    ln_apply<float, bf16, bf16><<<dim3(256, CB), blk, 0, stream>>>(x, attn, stats, hbuf, perBatch);

    // FFN (ff1 overwrites q..attn region — all dead by now)
    gemm_bias<bf16><<<dim3(CH / 64, BL / 64), blk, 0, stream>>>(hbuf, w1, b1, ff1, BL, CH, CD, 1);
    gemm_bias<bf16><<<dim3(CD / 64, BL / 64), blk, 0, stream>>>(ff1,  w2, b2, ff2, BL, CD, CH, 0);

    // residual + joint-(L,C) LayerNorm -> out (fp32)
    ln_reduce<bf16, bf16><<<dim3(256, CB), blk, 0, stream>>>(hbuf, ff2, stats + 8, perBatch);
    ln_apply<bf16, bf16, float><<<dim3(256, CB), blk, 0, stream>>>(hbuf, ff2, stats + 8, (float*)d_out, perBatch);
}

// Round 3
// 490.323 us; speedup vs baseline: 8.1370x; 8.1370x over previous
//
#include <hip/hip_runtime.h>
#include <hip/hip_bf16.h>

typedef __hip_bfloat16 bf16;
typedef __attribute__((ext_vector_type(8))) short short8;
typedef __attribute__((ext_vector_type(4))) float f32x4;

#define CB 2
#define CL 2048
#define CD 1024
#define CH 4096
#define NHEADS 16
#define DH 64

// ---------------------------------------------------------------------------
// helpers
// ---------------------------------------------------------------------------
__device__ __forceinline__ short f2bs(float f) {
    __hip_bfloat16 h = __float2bfloat16(f);
    return *reinterpret_cast<short*>(&h);
}
__device__ __forceinline__ float bs2f(short s) {
    __hip_bfloat16 h = *reinterpret_cast<__hip_bfloat16*>(&s);
    return __bfloat162float(h);
}
__device__ __forceinline__ float ldf(const float* p, size_t i) { return p[i]; }
__device__ __forceinline__ float ldf(const bf16* p, size_t i) { return __bfloat162float(p[i]); }

// async global->LDS, 16B per lane (m97 idiom). LDS dest must be base+lane*16.
__device__ __forceinline__ void async_copy16(const short* g, short* l) {
    __builtin_amdgcn_global_load_lds((const __attribute__((address_space(1))) unsigned int*)g,
                                     (__attribute__((address_space(3))) unsigned int*)l,
                                     16, 0, 0);
}

__global__ void zero_stats_kernel(float* s) {
    if (threadIdx.x < 16) s[threadIdx.x] = 0.0f;
}

__global__ void pack_bias_kernel(const float* __restrict__ bq, const float* __restrict__ bk,
                                 const float* __restrict__ bv, float* __restrict__ o) {
    int i = blockIdx.x * 256 + threadIdx.x;
    if (i < 3072) o[i] = i < 1024 ? bq[i] : (i < 2048 ? bk[i - 1024] : bv[i - 2048]);
}

// in[K][N] f32 -> out[row_off + n][k] bf16 (out row stride = K)
__global__ void transpose_cvt(const float* __restrict__ in, short* __restrict__ out,
                              int K, int N, int row_off) {
    __shared__ float T[32][33];
    const int tx = threadIdx.x & 31, ty = threadIdx.x >> 5; // ty 0..7
    const int k0 = blockIdx.y * 32, n0 = blockIdx.x * 32;
    #pragma unroll
    for (int i = 0; i < 4; ++i)
        T[ty + i * 8][tx] = in[(size_t)(k0 + ty + i * 8) * N + n0 + tx];
    __syncthreads();
    #pragma unroll
    for (int i = 0; i < 4; ++i)
        out[(size_t)(row_off + n0 + ty + i * 8) * K + k0 + tx] = f2bs(T[tx][ty + i * 8]);
}

// ---------------------------------------------------------------------------
// MFMA GEMM (m97 structure): C[M,N] = A[M,K] @ Bt[N,K]^T + bias, bf16 out.
// 128x128 tile, BK=32, 256 threads (4 waves, each 64x64 = 4x4 16-tiles).
// A_F32: A is fp32, register-staged+cvt. LN2EPI: C += read(C-site h), in-place
// write s=h+v into C(=hbuf) and atomicAdd (sum,sumsq) partials into stats.
// ---------------------------------------------------------------------------
template <int A_F32, int RELU, int LN2EPI>
__launch_bounds__(256)
__global__ void gemm_mfma(const void* __restrict__ Av,
                          const short* __restrict__ Bt,
                          const float* __restrict__ bias,
                          short* __restrict__ C,
                          int M, int N, int K,
                          float* __restrict__ stats) {
    __shared__ short As[128 * 32];
    __shared__ short Bs[128 * 32];
    __shared__ float red[8];

    const int tid = threadIdx.x;
    const int wave = tid >> 6, lane = tid & 63, quad = lane >> 4, lm = lane & 15;
    const int wm = (wave & 1) * 64, wn = (wave >> 1) * 64;
    const int row0 = blockIdx.y * 128, col0 = blockIdx.x * 128;

    f32x4 acc[4][4];
    #pragma unroll
    for (int i = 0; i < 4; ++i)
        #pragma unroll
        for (int j = 0; j < 4; ++j) { f32x4 z = {0.f, 0.f, 0.f, 0.f}; acc[i][j] = z; }

    for (int k0 = 0; k0 < K; k0 += 32) {
        if (A_F32) {
            const float* A = (const float*)Av;
            #pragma unroll
            for (int t = 0; t < 2; ++t) {
                int c = tid + t * 256;
                int r = c >> 2, sg = c & 3;
                const float* gp = A + (size_t)(row0 + r) * K + k0 + sg * 8;
                float4 f0 = *(const float4*)gp;
                float4 f1 = *(const float4*)(gp + 4);
                short8 h;
                h[0] = f2bs(f0.x); h[1] = f2bs(f0.y); h[2] = f2bs(f0.z); h[3] = f2bs(f0.w);
                h[4] = f2bs(f1.x); h[5] = f2bs(f1.y); h[6] = f2bs(f1.z); h[7] = f2bs(f1.w);
                *(short8*)&As[c * 8] = h;
            }
        } else {
            const short* A = (const short*)Av;
            #pragma unroll
            for (int t = 0; t < 2; ++t) {
                int c = tid + t * 256;
                int r = c >> 2, sg = c & 3;
                async_copy16(A + (size_t)(row0 + r) * K + k0 + sg * 8, &As[c * 8]);
            }
        }
        #pragma unroll
        for (int t = 0; t < 2; ++t) {
            int c = tid + t * 256;
            int r = c >> 2, sg = c & 3;
            async_copy16(Bt + (size_t)(col0 + r) * K + k0 + sg * 8, &Bs[c * 8]);
        }
        __syncthreads();

        short8 af[4], bfr[4];
        #pragma unroll
        for (int mt = 0; mt < 4; ++mt)
            af[mt] = *(const short8*)&As[(wm + mt * 16 + lm) * 32 + quad * 8];
        #pragma unroll
        for (int nt = 0; nt < 4; ++nt)
            bfr[nt] = *(const short8*)&Bs[(wn + nt * 16 + lm) * 32 + quad * 8];
        #pragma unroll
        for (int mt = 0; mt < 4; ++mt)
            #pragma unroll
            for (int nt = 0; nt < 4; ++nt)
                acc[mt][nt] = __builtin_amdgcn_mfma_f32_16x16x32_bf16(af[mt], bfr[nt], acc[mt][nt], 0, 0, 0);
        __syncthreads();
    }

    float s1 = 0.f, s2 = 0.f;
    #pragma unroll
    for (int mt = 0; mt < 4; ++mt) {
        #pragma unroll
        for (int nt = 0; nt < 4; ++nt) {
            const int col = col0 + wn + nt * 16 + lm;
            const float bv = bias[col];
            #pragma unroll
            for (int r = 0; r < 4; ++r) {
                const int row = row0 + wm + mt * 16 + quad * 4 + r;
                float v = acc[mt][nt][r] + bv;
                if (RELU) v = fmaxf(v, 0.f);
                const size_t idx = (size_t)row * N + col;
                if (LN2EPI) {
                    v += bs2f(C[idx]);     // s = h + (ff2 + b2)
                    s1 += v; s2 += v * v;
                }
                C[idx] = f2bs(v);
            }
        }
    }
    if (LN2EPI) {
        #pragma unroll
        for (int off = 1; off <= 32; off <<= 1) {
            s1 += __shfl_xor(s1, off, 64);
            s2 += __shfl_xor(s2, off, 64);
        }
        if (lane == 0) { red[wave] = s1; red[4 + wave] = s2; }
        __syncthreads();
        if (tid == 0) {
            const int batch = (row0 >= CL) ? 1 : 0;
            atomicAdd(&stats[batch * 2 + 0], red[0] + red[1] + red[2] + red[3]);
            atomicAdd(&stats[batch * 2 + 1], red[4] + red[5] + red[6] + red[7]);
        }
    }
}

// ---------------------------------------------------------------------------
// Flash-lite MFMA attention. Block = 64 Q rows of one (b,h); 4 waves x 16 rows.
// K-tile = 32 keys. qkv packed [B*L][3072]: q|k|v each 1024 cols, head h at +h*64.
// No max-subtraction (scores bounded, exp safe); divide by rowsum at the end.
// ---------------------------------------------------------------------------
__launch_bounds__(256)
__global__ void attn_mfma(const short* __restrict__ qkv, short* __restrict__ O) {
    __shared__ short Ks[32 * 88];      // K tile row-major [key][dh64], 176B rows
    __shared__ short Vt[64 * 40];      // V^T [dh][key32], 80B rows
    __shared__ short Ps[4][16 * 40];   // per-wave P [qrow16][key32], 80B rows

    const int tid = threadIdx.x;
    const int wave = tid >> 6, lane = tid & 63, quad = lane >> 4, lm = lane & 15;
    const int qb = blockIdx.x, h = blockIdx.y, b = blockIdx.z;
    const size_t RS = 3072;
    const int hoff = h * DH;
    const size_t rowb = (size_t)b * CL;

    // Q A-frags (k=0..31, 32..63), rows qb*64 + wave*16 + lm
    const size_t qbase = (rowb + qb * 64 + wave * 16 + lm) * RS + hoff;
    const short8 aq0 = *(const short8*)(qkv + qbase + quad * 8);
    const short8 aq1 = *(const short8*)(qkv + qbase + 32 + quad * 8);

    f32x4 oacc[4];
    #pragma unroll
    for (int i = 0; i < 4; ++i) { f32x4 z = {0.f, 0.f, 0.f, 0.f}; oacc[i] = z; }
    float lsum[4] = {0.f, 0.f, 0.f, 0.f};

    const int key_c = tid >> 3, seg = tid & 7;   // staging: 1 chunk of 16B each

    for (int kt = 0; kt < CL / 32; ++kt) {
        const size_t krow = (rowb + kt * 32 + key_c) * RS + hoff + seg * 8;
        const short8 kk = *(const short8*)(qkv + krow + 1024);
        *(short8*)&Ks[key_c * 88 + seg * 8] = kk;
        const short8 vv = *(const short8*)(qkv + krow + 2048);
        #pragma unroll
        for (int j = 0; j < 8; ++j) Vt[(seg * 8 + j) * 40 + key_c] = vv[j];
        __syncthreads();

        #pragma unroll
        for (int nh = 0; nh < 2; ++nh) {
            const short8 bk0 = *(const short8*)&Ks[(nh * 16 + lm) * 88 + quad * 8];
            const short8 bk1 = *(const short8*)&Ks[(nh * 16 + lm) * 88 + 32 + quad * 8];
            f32x4 s = {0.f, 0.f, 0.f, 0.f};
            s = __builtin_amdgcn_mfma_f32_16x16x32_bf16(aq0, bk0, s, 0, 0, 0);
            s = __builtin_amdgcn_mfma_f32_16x16x32_bf16(aq1, bk1, s, 0, 0, 0);
            #pragma unroll
            for (int r = 0; r < 4; ++r) {
                const float p = __expf(s[r] * 0.125f);
                lsum[r] += p;
                Ps[wave][(quad * 4 + r) * 40 + nh * 16 + lm] = f2bs(p);
            }
        }
        // same-wave LDS producer->consumer (in-order DS pipe)
        const short8 pf = *(const short8*)&Ps[wave][lm * 40 + quad * 8];
        #pragma unroll
        for (int nt = 0; nt < 4; ++nt) {
            const short8 vf = *(const short8*)&Vt[(nt * 16 + lm) * 40 + quad * 8];
            oacc[nt] = __builtin_amdgcn_mfma_f32_16x16x32_bf16(pf, vf, oacc[nt], 0, 0, 0);
        }
        __syncthreads();
    }

    // rowsum reduce across the 16 lanes of each quad (cols of rows quad*4+r)
    #pragma unroll
    for (int off = 1; off <= 8; off <<= 1)
        #pragma unroll
        for (int r = 0; r < 4; ++r) lsum[r] += __shfl_xor(lsum[r], off, 64);

    #pragma unroll
    for (int nt = 0; nt < 4; ++nt)
        #pragma unroll
        for (int r = 0; r < 4; ++r)
            O[(size_t)(rowb + qb * 64 + wave * 16 + quad * 4 + r) * CD + hoff + nt * 16 + lm] =
                f2bs(oacc[nt][r] / lsum[r]);
}

// ---------------------------------------------------------------------------
// Joint-(L,C) LayerNorm pieces
// ---------------------------------------------------------------------------
template <typename TA, typename TB>
__global__ void ln_reduce(const TA* __restrict__ a, const TB* __restrict__ b,
                          float* __restrict__ stats, int perBatch) {
    const int bId = blockIdx.y;
    const size_t base = (size_t)bId * perBatch;
    const int tid = threadIdx.x;
    float s1 = 0.f, s2 = 0.f;
    for (int i = blockIdx.x * 256 + tid; i < perBatch; i += gridDim.x * 256) {
        float v = ldf(a, base + i) + ldf(b, base + i);
        s1 += v; s2 += v * v;
    }
    #pragma unroll
    for (int off = 1; off <= 32; off <<= 1) {
        s1 += __shfl_xor(s1, off, 64);
        s2 += __shfl_xor(s2, off, 64);
    }
    __shared__ float r1[4], r2[4];
    const int w = tid >> 6, lane = tid & 63;
    if (lane == 0) { r1[w] = s1; r2[w] = s2; }
    __syncthreads();
    if (tid == 0) {
        atomicAdd(&stats[bId * 2 + 0], r1[0] + r1[1] + r1[2] + r1[3]);
        atomicAdd(&stats[bId * 2 + 1], r2[0] + r2[1] + r2[2] + r2[3]);
    }
}

__global__ void ln_apply_pair(const float* __restrict__ a, const bf16* __restrict__ b,
                              const float* __restrict__ stats, bf16* __restrict__ out,
                              int perBatch) {
    const int bId = blockIdx.y;
    const size_t base = (size_t)bId * perBatch;
    const float n = (float)perBatch;
    const float mean = stats[bId * 2 + 0] / n;
    const float var  = stats[bId * 2 + 1] / n - mean * mean + 1e-5f;
    const float inv  = rsqrtf(var);
    for (int i = blockIdx.x * 256 + threadIdx.x; i < perBatch; i += gridDim.x * 256) {
        float v = a[base + i] + __bfloat162float(b[base + i]);
        out[base + i] = __float2bfloat16((v - mean) * inv);
    }
}

__global__ void ln_apply_single(const bf16* __restrict__ s, const float* __restrict__ stats,
                                float* __restrict__ out, int perBatch) {
    const int bId = blockIdx.y;
    const size_t base = (size_t)bId * perBatch;
    const float n = (float)perBatch;
    const float mean = stats[bId * 2 + 0] / n;
    const float var  = stats[bId * 2 + 1] / n - mean * mean + 1e-5f;
    const float inv  = rsqrtf(var);
    for (int i = blockIdx.x * 256 + threadIdx.x; i < perBatch; i += gridDim.x * 256)
        out[base + i] = (__bfloat162float(s[base + i]) - mean) * inv;
}

// ---------------------------------------------------------------------------
extern "C" void kernel_launch(void* const* d_in, const int* in_sizes, int n_in,
                              void* d_out, int out_size, void* d_ws, size_t ws_size,
                              hipStream_t stream) {
    const float* x  = (const float*)d_in[0];
    const float* wq = (const float*)d_in[1];
    const float* bq = (const float*)d_in[2];
    const float* wk = (const float*)d_in[3];
    const float* bk = (const float*)d_in[4];
    const float* wv = (const float*)d_in[5];
    const float* bv = (const float*)d_in[6];
    const float* w1 = (const float*)d_in[7];
    const float* b1 = (const float*)d_in[8];
    const float* w2 = (const float*)d_in[9];
    const float* b2 = (const float*)d_in[10];

    const int BL = CB * CL;         // 4096
    const int perBatch = CL * CD;   // 2M

    // ws layout, peak 48MB + 64B (proven budget):
    //   [0,8):   Wqkvt(6MB)+bqkv  -> reused: w1t, then w2t   (8MB region)
    //   [8,32):  qkv [4096][3072]  -> reused by ff1
    //   [32,40): attn              -> reused by ff1
    //   [8,40):  ff1 [4096][4096]
    //   [40,48): hbuf (LN1 out; FFN2 writes s=h+ff2 in-place)
    //   [48MB):  stats (16 f32): [0..3] LN1, [8..11] LN2
    char* ws = (char*)d_ws;
    const size_t MB = 1024 * 1024;
    short* Wqkvt = (short*)(ws);                 // [3072][1024]
    float* bqkv  = (float*)(ws + 6 * MB);        // 3072 f32 (within region 0)
    short* w1t   = (short*)(ws);                 // [4096][1024]
    short* w2t   = (short*)(ws);                 // [1024][4096]
    short* qkv   = (short*)(ws + 8 * MB);        // [4096][3072]
    short* attnb = (short*)(ws + 32 * MB);       // [4096][1024]
    short* ff1   = (short*)(ws + 8 * MB);        // [4096][4096]
    short* hbuf  = (short*)(ws + 40 * MB);       // [4096][1024]
    float* stats = (float*)(ws + 48 * MB);

    dim3 blk(256);

    zero_stats_kernel<<<1, 64, 0, stream>>>(stats);
    pack_bias_kernel<<<12, 256, 0, stream>>>(bq, bk, bv, bqkv);

    // weight transposes (fp32 -> bf16, [K][N] -> [N][K])
    transpose_cvt<<<dim3(32, 32), blk, 0, stream>>>(wq, Wqkvt, CD, CD, 0);
    transpose_cvt<<<dim3(32, 32), blk, 0, stream>>>(wk, Wqkvt, CD, CD, 1024);
    transpose_cvt<<<dim3(32, 32), blk, 0, stream>>>(wv, Wqkvt, CD, CD, 2048);

    // fused QKV projection: [4096][1024] @ [1024][3072] -> qkv [4096][3072]
    gemm_mfma<1, 0, 0><<<dim3(3072 / 128, BL / 128), blk, 0, stream>>>(
        x, Wqkvt, bqkv, qkv, BL, 3072, CD, nullptr);

    // attention
    attn_mfma<<<dim3(CL / 64, NHEADS, CB), blk, 0, stream>>>(qkv, attnb);

    // residual + LN1 -> hbuf
    ln_reduce<float, bf16><<<dim3(256, CB), blk, 0, stream>>>(x, (const bf16*)attnb, stats, perBatch);
    ln_apply_pair<<<dim3(256, CB), blk, 0, stream>>>(x, (const bf16*)attnb, stats, (bf16*)hbuf, perBatch);

    // FFN1: hbuf @ w1t^T + b1, ReLU -> ff1   (w1t overwrites Wqkvt region)
    transpose_cvt<<<dim3(128, 32), blk, 0, stream>>>(w1, w1t, CD, CH, 0);
    gemm_mfma<0, 1, 0><<<dim3(CH / 128, BL / 128), blk, 0, stream>>>(
        ff1 == nullptr ? nullptr : hbuf, w1t, b1, ff1, BL, CH, CD, nullptr);

    // FFN2: ff1 @ w2t^T + b2, + hbuf residual in-place, + LN2 partial stats
    transpose_cvt<<<dim3(32, 128), blk, 0, stream>>>(w2, w2t, CH, CD, 0);
    gemm_mfma<0, 0, 1><<<dim3(CD / 128, BL / 128), blk, 0, stream>>>(
        ff1, w2t, b2, hbuf, BL, CD, CH, stats + 8);

    // LN2 apply -> out (fp32)
    ln_apply_single<<<dim3(256, CB), blk, 0, stream>>>((const bf16*)hbuf, stats + 8, (float*)d_out, perBatch);
}

// Round 4
// 437.662 us; speedup vs baseline: 9.1160x; 1.1203x over previous
//
#include <hip/hip_runtime.h>
#include <hip/hip_bf16.h>

typedef __hip_bfloat16 bf16;
typedef __attribute__((ext_vector_type(8))) short short8;
typedef __attribute__((ext_vector_type(4))) short short4v;
typedef __attribute__((ext_vector_type(4))) float f32x4;

#define CB 2
#define CL 2048
#define CD 1024
#define CH 4096
#define NHEADS 16
#define DH 64

__device__ __forceinline__ short f2bs(float f) {
    __hip_bfloat16 h = __float2bfloat16(f);
    return *reinterpret_cast<short*>(&h);
}
__device__ __forceinline__ float bs2f(short s) {
    __hip_bfloat16 h = *reinterpret_cast<__hip_bfloat16*>(&s);
    return __bfloat162float(h);
}

__device__ __forceinline__ void async_copy16(const short* g, short* l) {
    __builtin_amdgcn_global_load_lds((const __attribute__((address_space(1))) unsigned int*)g,
                                     (__attribute__((address_space(3))) unsigned int*)l,
                                     16, 0, 0);
}

__global__ void zero_stats_kernel(float* s) {
    if (threadIdx.x < 16) s[threadIdx.x] = 0.0f;
}

__global__ void pack_bias_kernel(const float* __restrict__ bq, const float* __restrict__ bk,
                                 const float* __restrict__ bv, float* __restrict__ o) {
    int i = blockIdx.x * 256 + threadIdx.x;
    if (i < 3072) o[i] = i < 1024 ? bq[i] : (i < 2048 ? bk[i - 1024] : bv[i - 2048]);
}

// x fp32 -> bf16, 4 elems/thread
__global__ void cvt_x_kernel(const float* __restrict__ x, short* __restrict__ o) {
    const int i = (blockIdx.x * 256 + threadIdx.x) * 4;
    const float4 v = *(const float4*)&x[i];
    short4v s; s[0] = f2bs(v.x); s[1] = f2bs(v.y); s[2] = f2bs(v.z); s[3] = f2bs(v.w);
    *(short4v*)&o[i] = s;
}

// in[K][N] f32 -> out[row_off + n][k] bf16 (out row stride = K)
__global__ void transpose_cvt(const float* __restrict__ in, short* __restrict__ out,
                              int K, int N, int row_off) {
    __shared__ float T[32][33];
    const int tx = threadIdx.x & 31, ty = threadIdx.x >> 5;
    const int k0 = blockIdx.y * 32, n0 = blockIdx.x * 32;
    #pragma unroll
    for (int i = 0; i < 4; ++i)
        T[ty + i * 8][tx] = in[(size_t)(k0 + ty + i * 8) * N + n0 + tx];
    __syncthreads();
    #pragma unroll
    for (int i = 0; i < 4; ++i)
        out[(size_t)(row_off + n0 + ty + i * 8) * K + k0 + tx] = f2bs(T[tx][ty + i * 8]);
}

// ---------------------------------------------------------------------------
// MFMA GEMM, m97 structure. BM=128 fixed, BN in {128,64}. 256 threads.
// EPI 0: C[row*N+col] = act(acc+bias)            (RELU template)
// EPI 1: QKV split: col<2048 -> qk[row*2048+col]; col>=2048 -> vT transposed
// EPI 2: LN2: v += C(hbuf); in-place write; atomicAdd (sum,sumsq) -> stats
// ---------------------------------------------------------------------------
template <int BN, int RELU, int EPI>
__launch_bounds__(256)
__global__ void gemm_mfma(const short* __restrict__ A,
                          const short* __restrict__ Bt,
                          const float* __restrict__ bias,
                          short* __restrict__ C,
                          short* __restrict__ C2,
                          int M, int N, int K,
                          float* __restrict__ stats) {
    constexpr int NT = BN / 32;            // n-tiles per wave
    __shared__ short As[128 * 32];
    __shared__ short Bs[BN * 32];
    __shared__ float red[8];

    const int tid = threadIdx.x;
    const int wave = tid >> 6, lane = tid & 63, quad = lane >> 4, lm = lane & 15;
    const int wm = (wave & 1) * 64, wn = (wave >> 1) * (NT * 16);
    const int row0 = blockIdx.y * 128, col0 = blockIdx.x * BN;

    f32x4 acc[4][NT];
    #pragma unroll
    for (int i = 0; i < 4; ++i)
        #pragma unroll
        for (int j = 0; j < NT; ++j) { f32x4 z = {0.f, 0.f, 0.f, 0.f}; acc[i][j] = z; }

    for (int k0 = 0; k0 < K; k0 += 32) {
        #pragma unroll
        for (int t = 0; t < 2; ++t) {
            int c = tid + t * 256;
            int r = c >> 2, sg = c & 3;
            async_copy16(A + (size_t)(row0 + r) * K + k0 + sg * 8, &As[c * 8]);
        }
        #pragma unroll
        for (int t = 0; t < BN / 64; ++t) {
            int c = tid + t * 256;
            int r = c >> 2, sg = c & 3;
            async_copy16(Bt + (size_t)(col0 + r) * K + k0 + sg * 8, &Bs[c * 8]);
        }
        __syncthreads();

        short8 af[4], bfr[NT];
        #pragma unroll
        for (int mt = 0; mt < 4; ++mt)
            af[mt] = *(const short8*)&As[(wm + mt * 16 + lm) * 32 + quad * 8];
        #pragma unroll
        for (int nt = 0; nt < NT; ++nt)
            bfr[nt] = *(const short8*)&Bs[(wn + nt * 16 + lm) * 32 + quad * 8];
        #pragma unroll
        for (int mt = 0; mt < 4; ++mt)
            #pragma unroll
            for (int nt = 0; nt < NT; ++nt)
                acc[mt][nt] = __builtin_amdgcn_mfma_f32_16x16x32_bf16(af[mt], bfr[nt], acc[mt][nt], 0, 0, 0);
        __syncthreads();
    }

    float s1 = 0.f, s2 = 0.f;
    #pragma unroll
    for (int mt = 0; mt < 4; ++mt) {
        #pragma unroll
        for (int nt = 0; nt < NT; ++nt) {
            const int col = col0 + wn + nt * 16 + lm;
            const float bv = bias[col];
            const int rowb = row0 + wm + mt * 16 + quad * 4;
            if (EPI == 1 && col >= 2048) {
                // vT[b][col-2048][l], 4 consecutive l per lane
                const int b = row0 >> 11;
                const int l0 = rowb & (CL - 1);
                short4v sv;
                #pragma unroll
                for (int r = 0; r < 4; ++r) sv[r] = f2bs(acc[mt][nt][r] + bv);
                *(short4v*)&C2[(size_t)b * CD * CL + (size_t)(col - 2048) * CL + l0] = sv;
            } else {
                #pragma unroll
                for (int r = 0; r < 4; ++r) {
                    float v = acc[mt][nt][r] + bv;
                    if (RELU) v = fmaxf(v, 0.f);
                    const int ld = (EPI == 1) ? 2048 : N;
                    const size_t idx = (size_t)(rowb + r) * ld + col;
                    if (EPI == 2) {
                        v += bs2f(C[idx]);
                        s1 += v; s2 += v * v;
                    }
                    C[idx] = f2bs(v);
                }
            }
        }
    }
    if (EPI == 2) {
        #pragma unroll
        for (int off = 1; off <= 32; off <<= 1) {
            s1 += __shfl_xor(s1, off, 64);
            s2 += __shfl_xor(s2, off, 64);
        }
        if (lane == 0) { red[wave] = s1; red[4 + wave] = s2; }
        __syncthreads();
        if (tid == 0) {
            const int batch = row0 >> 11;
            atomicAdd(&stats[batch * 2 + 0], red[0] + red[1] + red[2] + red[3]);
            atomicAdd(&stats[batch * 2 + 1], red[4] + red[5] + red[6] + red[7]);
        }
    }
}

// ---------------------------------------------------------------------------
// Attention, S^T formulation. Block = 128 q-rows of one (b,h); 4 waves x 32 q.
// S^T = K.Q^T  (A = K rows from LDS, B = Q rows in regs)     [16x16x32 MFMA]
// P^T B-frag == exp(S^T C-layout) in-register (no LDS round trip).
// O^T = V^T.P^T with zero-padded k-half                      [16x16x32 MFMA]
// Epilogue: o/rowsum + x residual -> sbuf (s = x+attn), LN1 partial stats.
// ---------------------------------------------------------------------------
__launch_bounds__(256)
__global__ void attn_mfma(const short* __restrict__ qk,
                          const short* __restrict__ vT,
                          const float* __restrict__ x,
                          short* __restrict__ sbuf,
                          float* __restrict__ stats) {
    __shared__ short Ks[2 * 16 * 32];     // [khalf][key16][32 dh]  2 KB
    __shared__ short Vt[64 * 40];         // [dh64][key16 +pad]     5 KB
    __shared__ float red[8];

    const int tid = threadIdx.x;
    const int wave = tid >> 6, lane = tid & 63, quad = lane >> 4, lm = lane & 15;
    const int h = blockIdx.y, b = blockIdx.z;
    const int hoff = h * DH;
    const size_t rowb = (size_t)b * CL;
    const int qbase0 = blockIdx.x * 128 + wave * 32;      // +qt*16+lm

    // Q B-frags: bq[qt][kf], lane lm = Q row (qbase+lm)
    short8 bq[2][2];
    #pragma unroll
    for (int qt = 0; qt < 2; ++qt)
        #pragma unroll
        for (int kf = 0; kf < 2; ++kf)
            bq[qt][kf] = *(const short8*)(qk + (rowb + qbase0 + qt * 16 + lm) * 2048 + hoff + kf * 32 + quad * 8);

    f32x4 oacc[2][4];
    #pragma unroll
    for (int qt = 0; qt < 2; ++qt)
        #pragma unroll
        for (int mt = 0; mt < 4; ++mt) { f32x4 z = {0.f, 0.f, 0.f, 0.f}; oacc[qt][mt] = z; }
    float lsum[2] = {0.f, 0.f};

    const int vrow = tid >> 2, vseg = tid & 3;            // V staging: all 256
    const int kkey = (tid >> 2) & 15, kseg = tid & 3, ksub = tid >> 6; // K: tid<128

    for (int kt = 0; kt < CL / 16; ++kt) {
        if (tid < 128)
            async_copy16(qk + (rowb + kt * 16 + kkey) * 2048 + 1024 + hoff + ksub * 32 + kseg * 8,
                         &Ks[tid * 8]);
        {
            const short4v vv = *(const short4v*)(vT + (size_t)b * CD * CL +
                                                 (size_t)(hoff + vrow) * CL + kt * 16 + vseg * 4);
            *(short4v*)&Vt[vrow * 40 + vseg * 4] = vv;
        }
        __syncthreads();

        const short8 afk0 = *(const short8*)&Ks[lm * 32 + quad * 8];
        const short8 afk1 = *(const short8*)&Ks[512 + lm * 32 + quad * 8];

        short8 vf[4];
        #pragma unroll
        for (int mt = 0; mt < 4; ++mt) {
            const short4v vl = *(const short4v*)&Vt[(mt * 16 + lm) * 40 + quad * 4];
            short8 v8; v8[0] = vl[0]; v8[1] = vl[1]; v8[2] = vl[2]; v8[3] = vl[3];
            v8[4] = 0; v8[5] = 0; v8[6] = 0; v8[7] = 0;
            vf[mt] = v8;
        }

        #pragma unroll
        for (int qt = 0; qt < 2; ++qt) {
            f32x4 st = {0.f, 0.f, 0.f, 0.f};
            st = __builtin_amdgcn_mfma_f32_16x16x32_bf16(afk0, bq[qt][0], st, 0, 0, 0);
            st = __builtin_amdgcn_mfma_f32_16x16x32_bf16(afk1, bq[qt][1], st, 0, 0, 0);
            short8 pf;
            #pragma unroll
            for (int r = 0; r < 4; ++r) {
                const float p = __expf(st[r] * 0.125f);
                lsum[qt] += p;
                pf[r] = f2bs(p);
            }
            pf[4] = 0; pf[5] = 0; pf[6] = 0; pf[7] = 0;
            #pragma unroll
            for (int mt = 0; mt < 4; ++mt)
                oacc[qt][mt] = __builtin_amdgcn_mfma_f32_16x16x32_bf16(vf[mt], pf, oacc[qt][mt], 0, 0, 0);
        }
        __syncthreads();
    }

    // rowsum: reduce across quads (lanes lm, lm+16, lm+32, lm+48)
    #pragma unroll
    for (int qt = 0; qt < 2; ++qt) {
        lsum[qt] += __shfl_xor(lsum[qt], 16, 64);
        lsum[qt] += __shfl_xor(lsum[qt], 32, 64);
    }

    // epilogue: s = x + O, LN1 partial stats. lane holds O^T[dh=mt*16+quad*4+r][q=lm]
    float s1 = 0.f, s2 = 0.f;
    #pragma unroll
    for (int qt = 0; qt < 2; ++qt) {
        const float inv = 1.0f / lsum[qt];
        const size_t grow = rowb + qbase0 + qt * 16 + lm;
        #pragma unroll
        for (int mt = 0; mt < 4; ++mt) {
            const size_t base = grow * CD + hoff + mt * 16 + quad * 4;
            const float4 xv = *(const float4*)&x[base];
            const float xa[4] = {xv.x, xv.y, xv.z, xv.w};
            short4v sv;
            #pragma unroll
            for (int r = 0; r < 4; ++r) {
                const float s = xa[r] + oacc[qt][mt][r] * inv;
                s1 += s; s2 += s * s;
                sv[r] = f2bs(s);
            }
            *(short4v*)&sbuf[base] = sv;
        }
    }
    #pragma unroll
    for (int off = 1; off <= 32; off <<= 1) {
        s1 += __shfl_xor(s1, off, 64);
        s2 += __shfl_xor(s2, off, 64);
    }
    if (lane == 0) { red[wave] = s1; red[4 + wave] = s2; }
    __syncthreads();
    if (tid == 0) {
        atomicAdd(&stats[b * 2 + 0], red[0] + red[1] + red[2] + red[3]);
        atomicAdd(&stats[b * 2 + 1], red[4] + red[5] + red[6] + red[7]);
    }
}

// ---------------------------------------------------------------------------
// LN apply (stats already summed): out = (s - mean) * rsqrt(var + eps)
// ---------------------------------------------------------------------------
template <typename TO>
__global__ void ln_apply(const bf16* __restrict__ s, const float* __restrict__ stats,
                         TO* __restrict__ out, int perBatch) {
    const int bId = blockIdx.y;
    const size_t base = (size_t)bId * perBatch;
    const float n = (float)perBatch;
    const float mean = stats[bId * 2 + 0] / n;
    const float var  = stats[bId * 2 + 1] / n - mean * mean + 1e-5f;
    const float inv  = rsqrtf(var);
    for (int i = blockIdx.x * 256 + threadIdx.x; i < perBatch; i += gridDim.x * 256) {
        const float v = (__bfloat162float(s[base + i]) - mean) * inv;
        if (sizeof(TO) == 4) ((float*)out)[base + i] = v;
        else ((bf16*)out)[base + i] = __float2bfloat16(v);
    }
}

// ---------------------------------------------------------------------------
extern "C" void kernel_launch(void* const* d_in, const int* in_sizes, int n_in,
                              void* d_out, int out_size, void* d_ws, size_t ws_size,
                              hipStream_t stream) {
    const float* x  = (const float*)d_in[0];
    const float* wq = (const float*)d_in[1];
    const float* bq = (const float*)d_in[2];
    const float* wk = (const float*)d_in[3];
    const float* bk = (const float*)d_in[4];
    const float* wv = (const float*)d_in[5];
    const float* bv = (const float*)d_in[6];
    const float* w1 = (const float*)d_in[7];
    const float* b1 = (const float*)d_in[8];
    const float* w2 = (const float*)d_in[9];
    const float* b2 = (const float*)d_in[10];

    const int BL = CB * CL;         // 4096
    const int perBatch = CL * CD;   // 2M

    // ws layout, peak 48MB + 64B (proven budget):
    //   [0,8):   weights: Wqkvt(6MB)+bqkv -> w1t -> w2t
    //   [8,16):  xbf            (dead after QKV gemm)
    //   [16,32): qk [4096][2048] (dead after attn)
    //   [32,40): vT [2][1024][2048] (dead after attn)
    //   [8,40):  ff1 [4096][4096] (reuse)
    //   [40,48): sbuf/hbuf (attn writes s; ln_apply in-place -> h; FFN2 -> s2)
    //   [48MB):  stats (16 f32): [0..3] LN1, [8..11] LN2
    char* ws = (char*)d_ws;
    const size_t MB = 1024 * 1024;
    short* Wqkvt = (short*)(ws);
    float* bqkv  = (float*)(ws + 6 * MB);
    short* w1t   = (short*)(ws);
    short* w2t   = (short*)(ws);
    short* xbf   = (short*)(ws + 8 * MB);
    short* qkb   = (short*)(ws + 16 * MB);
    short* vT    = (short*)(ws + 32 * MB);
    short* ff1   = (short*)(ws + 8 * MB);
    short* hbuf  = (short*)(ws + 40 * MB);
    float* stats = (float*)(ws + 48 * MB);

    dim3 blk(256);

    zero_stats_kernel<<<1, 64, 0, stream>>>(stats);
    cvt_x_kernel<<<BL * CD / 1024, blk, 0, stream>>>(x, xbf);
    pack_bias_kernel<<<12, blk, 0, stream>>>(bq, bk, bv, bqkv);
    transpose_cvt<<<dim3(32, 32), blk, 0, stream>>>(wq, Wqkvt, CD, CD, 0);
    transpose_cvt<<<dim3(32, 32), blk, 0, stream>>>(wk, Wqkvt, CD, CD, 1024);
    transpose_cvt<<<dim3(32, 32), blk, 0, stream>>>(wv, Wqkvt, CD, CD, 2048);

    // fused QKV: xbf @ Wqkvt^T; q,k -> qkb[row][2048], v -> vT[b][dh][l]
    gemm_mfma<128, 0, 1><<<dim3(3072 / 128, BL / 128), blk, 0, stream>>>(
        xbf, Wqkvt, bqkv, qkb, vT, BL, 3072, CD, nullptr);

    // attention + residual + LN1 stats -> hbuf region (s = x + attn)
    attn_mfma<<<dim3(CL / 128, NHEADS, CB), blk, 0, stream>>>(qkb, vT, x, hbuf, stats);

    // LN1 apply in-place: hbuf = (s - mean)/sd
    ln_apply<bf16><<<dim3(256, CB), blk, 0, stream>>>((const bf16*)hbuf, stats, (bf16*)hbuf, perBatch);

    // FFN1: hbuf @ w1t^T + b1, ReLU -> ff1
    transpose_cvt<<<dim3(128, 32), blk, 0, stream>>>(w1, w1t, CD, CH, 0);
    gemm_mfma<128, 1, 0><<<dim3(CH / 128, BL / 128), blk, 0, stream>>>(
        hbuf, w1t, b1, ff1, nullptr, BL, CH, CD, nullptr);

    // FFN2: ff1 @ w2t^T + b2 + hbuf residual in-place, LN2 stats (BN=64: 512 blocks)
    transpose_cvt<<<dim3(32, 128), blk, 0, stream>>>(w2, w2t, CH, CD, 0);
    gemm_mfma<64, 0, 2><<<dim3(CD / 64, BL / 128), blk, 0, stream>>>(
        ff1, w2t, b2, hbuf, nullptr, BL, CD, CH, stats + 8);

    // LN2 apply -> out fp32
    ln_apply<float><<<dim3(256, CB), blk, 0, stream>>>((const bf16*)hbuf, stats + 8, (float*)d_out, perBatch);
}

// Round 5
// 387.836 us; speedup vs baseline: 10.2872x; 1.1285x over previous
//
#include <hip/hip_runtime.h>
#include <hip/hip_bf16.h>

typedef __hip_bfloat16 bf16;
typedef __attribute__((ext_vector_type(8))) short short8;
typedef __attribute__((ext_vector_type(4))) short short4v;
typedef __attribute__((ext_vector_type(4))) float f32x4;

#define CB 2
#define CL 2048
#define CD 1024
#define CH 4096
#define NHEADS 16
#define DH 64

__device__ __forceinline__ short f2bs(float f) {
    __hip_bfloat16 h = __float2bfloat16(f);
    return *reinterpret_cast<short*>(&h);
}
__device__ __forceinline__ float bs2f(short s) {
    __hip_bfloat16 h = *reinterpret_cast<__hip_bfloat16*>(&s);
    return __bfloat162float(h);
}

__device__ __forceinline__ void async_copy16(const short* g, short* l) {
    __builtin_amdgcn_global_load_lds((const __attribute__((address_space(1))) unsigned int*)g,
                                     (__attribute__((address_space(3))) unsigned int*)l,
                                     16, 0, 0);
}

// pack QKV bias + zero LN stats (one launch)
__global__ void pack_bias_kernel(const float* __restrict__ bq, const float* __restrict__ bk,
                                 const float* __restrict__ bv, float* __restrict__ o,
                                 float* __restrict__ stats) {
    int i = blockIdx.x * 256 + threadIdx.x;
    if (i < 16) stats[i] = 0.0f;
    if (i < 3072) o[i] = i < 1024 ? bq[i] : (i < 2048 ? bk[i - 1024] : bv[i - 2048]);
}

// x fp32 -> bf16, 4 elems/thread
__global__ void cvt_x_kernel(const float* __restrict__ x, short* __restrict__ o) {
    const int i = (blockIdx.x * 256 + threadIdx.x) * 4;
    const float4 v = *(const float4*)&x[i];
    short4v s; s[0] = f2bs(v.x); s[1] = f2bs(v.y); s[2] = f2bs(v.z); s[3] = f2bs(v.w);
    *(short4v*)&o[i] = s;
}

// in[K][N] f32 -> out[row_off + n][k] bf16 (out row stride = K)
__global__ void transpose_cvt(const float* __restrict__ in, short* __restrict__ out,
                              int K, int N, int row_off) {
    __shared__ float T[32][33];
    const int tx = threadIdx.x & 31, ty = threadIdx.x >> 5;
    const int k0 = blockIdx.y * 32, n0 = blockIdx.x * 32;
    #pragma unroll
    for (int i = 0; i < 4; ++i)
        T[ty + i * 8][tx] = in[(size_t)(k0 + ty + i * 8) * N + n0 + tx];
    __syncthreads();
    #pragma unroll
    for (int i = 0; i < 4; ++i)
        out[(size_t)(row_off + n0 + ty + i * 8) * K + k0 + tx] = f2bs(T[tx][ty + i * 8]);
}

// 3 QKV weight transposes in one launch (z selects source)
__global__ void transpose_qkv(const float* __restrict__ wq, const float* __restrict__ wk,
                              const float* __restrict__ wv, short* __restrict__ out) {
    __shared__ float T[32][33];
    const int z = blockIdx.z;
    const float* in = z == 0 ? wq : (z == 1 ? wk : wv);
    const int row_off = z * 1024;
    const int tx = threadIdx.x & 31, ty = threadIdx.x >> 5;
    const int k0 = blockIdx.y * 32, n0 = blockIdx.x * 32;
    #pragma unroll
    for (int i = 0; i < 4; ++i)
        T[ty + i * 8][tx] = in[(size_t)(k0 + ty + i * 8) * CD + n0 + tx];
    __syncthreads();
    #pragma unroll
    for (int i = 0; i < 4; ++i)
        out[(size_t)(row_off + n0 + ty + i * 8) * CD + k0 + tx] = f2bs(T[tx][ty + i * 8]);
}

// ---------------------------------------------------------------------------
// MFMA GEMM, m97 structure. BM=128 fixed, BN in {128,64}. 256 threads.
// EPI 0: C = act(acc+bias)
// EPI 1: QKV split: col<2048 -> qk[row*2048+col]; col>=2048 -> vT[b][dh][l]
// EPI 2: LN2: v += C(hbuf); in-place write; atomicAdd (sum,sumsq) -> stats
// ---------------------------------------------------------------------------
template <int BN, int RELU, int EPI>
__launch_bounds__(256)
__global__ void gemm_mfma(const short* __restrict__ A,
                          const short* __restrict__ Bt,
                          const float* __restrict__ bias,
                          short* __restrict__ C,
                          short* __restrict__ C2,
                          int M, int N, int K,
                          float* __restrict__ stats) {
    constexpr int NT = BN / 32;
    __shared__ short As[128 * 32];
    __shared__ short Bs[BN * 32];
    __shared__ float red[8];

    const int tid = threadIdx.x;
    const int wave = tid >> 6, lane = tid & 63, quad = lane >> 4, lm = lane & 15;
    const int wm = (wave & 1) * 64, wn = (wave >> 1) * (NT * 16);
    const int row0 = blockIdx.y * 128, col0 = blockIdx.x * BN;

    f32x4 acc[4][NT];
    #pragma unroll
    for (int i = 0; i < 4; ++i)
        #pragma unroll
        for (int j = 0; j < NT; ++j) { f32x4 z = {0.f, 0.f, 0.f, 0.f}; acc[i][j] = z; }

    for (int k0 = 0; k0 < K; k0 += 32) {
        #pragma unroll
        for (int t = 0; t < 2; ++t) {
            int c = tid + t * 256;
            int r = c >> 2, sg = c & 3;
            async_copy16(A + (size_t)(row0 + r) * K + k0 + sg * 8, &As[c * 8]);
        }
        #pragma unroll
        for (int t = 0; t < BN / 64; ++t) {
            int c = tid + t * 256;
            int r = c >> 2, sg = c & 3;
            async_copy16(Bt + (size_t)(col0 + r) * K + k0 + sg * 8, &Bs[c * 8]);
        }
        __syncthreads();

        short8 af[4], bfr[NT];
        #pragma unroll
        for (int mt = 0; mt < 4; ++mt)
            af[mt] = *(const short8*)&As[(wm + mt * 16 + lm) * 32 + quad * 8];
        #pragma unroll
        for (int nt = 0; nt < NT; ++nt)
            bfr[nt] = *(const short8*)&Bs[(wn + nt * 16 + lm) * 32 + quad * 8];
        #pragma unroll
        for (int mt = 0; mt < 4; ++mt)
            #pragma unroll
            for (int nt = 0; nt < NT; ++nt)
                acc[mt][nt] = __builtin_amdgcn_mfma_f32_16x16x32_bf16(af[mt], bfr[nt], acc[mt][nt], 0, 0, 0);
        __syncthreads();
    }

    float s1 = 0.f, s2 = 0.f;
    #pragma unroll
    for (int mt = 0; mt < 4; ++mt) {
        #pragma unroll
        for (int nt = 0; nt < NT; ++nt) {
            const int col = col0 + wn + nt * 16 + lm;
            const float bv = bias[col];
            const int rowb = row0 + wm + mt * 16 + quad * 4;
            if (EPI == 1 && col >= 2048) {
                const int b = row0 >> 11;
                const int l0 = rowb & (CL - 1);
                short4v sv;
                #pragma unroll
                for (int r = 0; r < 4; ++r) sv[r] = f2bs(acc[mt][nt][r] + bv);
                *(short4v*)&C2[(size_t)b * CD * CL + (size_t)(col - 2048) * CL + l0] = sv;
            } else {
                #pragma unroll
                for (int r = 0; r < 4; ++r) {
                    float v = acc[mt][nt][r] + bv;
                    if (RELU) v = fmaxf(v, 0.f);
                    const int ld = (EPI == 1) ? 2048 : N;
                    const size_t idx = (size_t)(rowb + r) * ld + col;
                    if (EPI == 2) {
                        v += bs2f(C[idx]);
                        s1 += v; s2 += v * v;
                    }
                    C[idx] = f2bs(v);
                }
            }
        }
    }
    if (EPI == 2) {
        #pragma unroll
        for (int off = 1; off <= 32; off <<= 1) {
            s1 += __shfl_xor(s1, off, 64);
            s2 += __shfl_xor(s2, off, 64);
        }
        if (lane == 0) { red[wave] = s1; red[4 + wave] = s2; }
        __syncthreads();
        if (tid == 0) {
            const int batch = row0 >> 11;
            atomicAdd(&stats[batch * 2 + 0], red[0] + red[1] + red[2] + red[3]);
            atomicAdd(&stats[batch * 2 + 1], red[4] + red[5] + red[6] + red[7]);
        }
    }
}

// ---------------------------------------------------------------------------
// Attention, S^T formulation, KT=64 keys/iter, dense PV.
// Block = 128 q of one (b,h); 4 waves x 32 q (2 qt of 16).
// S^T = K.Q^T (A = K rows LDS, B = Q regs). exp in regs -> P.
// PV: pf/vf pair key-tiles 2p,2p+1 into full K=32 MFMAs (no zero padding).
// Epilogue: O/rowsum + x residual -> sbuf, LN1 partial stats.
// ---------------------------------------------------------------------------
__launch_bounds__(256)
__global__ void attn_mfma(const short* __restrict__ qk,
                          const short* __restrict__ vT,
                          const float* __restrict__ x,
                          short* __restrict__ sbuf,
                          float* __restrict__ stats) {
    __shared__ short Ks[64 * 64];       // [key64][dh64]      8 KB
    __shared__ short Vt[64 * 66];       // [dh64][key64 +2]   8.25 KB (odd dword stride)
    __shared__ float red[8];

    const int tid = threadIdx.x;
    const int wave = tid >> 6, lane = tid & 63, quad = lane >> 4, lm = lane & 15;
    const int h = blockIdx.y, b = blockIdx.z;
    const int hoff = h * DH;
    const size_t rowb = (size_t)b * CL;
    const size_t vbase = (size_t)b * CD * CL + (size_t)hoff * CL;
    const int qbase0 = blockIdx.x * 128 + wave * 32;

    // Q B-frags: bq[qt][kf], lane lm = q row
    short8 bq[2][2];
    #pragma unroll
    for (int qt = 0; qt < 2; ++qt)
        #pragma unroll
        for (int kf = 0; kf < 2; ++kf)
            bq[qt][kf] = *(const short8*)(qk + (rowb + qbase0 + qt * 16 + lm) * 2048 + hoff + kf * 32 + quad * 8);

    f32x4 oacc[2][4];
    #pragma unroll
    for (int qt = 0; qt < 2; ++qt)
        #pragma unroll
        for (int mt = 0; mt < 4; ++mt) { f32x4 z = {0.f, 0.f, 0.f, 0.f}; oacc[qt][mt] = z; }
    float lsum[2] = {0.f, 0.f};

    for (int kt = 0; kt < CL / 64; ++kt) {
        // stage K: 64 keys x 64 dh, async direct-to-LDS (2 x 16B per thread)
        #pragma unroll
        for (int t = 0; t < 2; ++t) {
            const int c = tid + t * 256;
            const int key = c >> 3, seg = c & 7;
            async_copy16(qk + (rowb + kt * 64 + key) * 2048 + 1024 + hoff + seg * 8, &Ks[c * 8]);
        }
        // stage V^T: 64 dh x 64 keys, padded rows (2 x 16B per thread)
        #pragma unroll
        for (int t = 0; t < 2; ++t) {
            const int c = tid + t * 256;
            const int row = c >> 3, seg = c & 7;
            const short8 vv = *(const short8*)(vT + vbase + (size_t)row * CL + kt * 64 + seg * 8);
            *(short8*)&Vt[row * 66 + seg * 8] = vv;
        }
        __syncthreads();

        // QK^T + exp for 4 key-tiles of 16
        float st[2][4][4];  // [qt][ktile][r]
        #pragma unroll
        for (int ktile = 0; ktile < 4; ++ktile) {
            const short8 a0 = *(const short8*)&Ks[(ktile * 16 + lm) * 64 + quad * 8];
            const short8 a1 = *(const short8*)&Ks[(ktile * 16 + lm) * 64 + 32 + quad * 8];
            #pragma unroll
            for (int qt = 0; qt < 2; ++qt) {
                f32x4 s = {0.f, 0.f, 0.f, 0.f};
                s = __builtin_amdgcn_mfma_f32_16x16x32_bf16(a0, bq[qt][0], s, 0, 0, 0);
                s = __builtin_amdgcn_mfma_f32_16x16x32_bf16(a1, bq[qt][1], s, 0, 0, 0);
                #pragma unroll
                for (int r = 0; r < 4; ++r) {
                    const float p = __expf(s[r] * 0.125f);
                    lsum[qt] += p;
                    st[qt][ktile][r] = p;
                }
            }
        }

        // PV: pair key-tiles (2p, 2p+1) -> dense K=32 MFMAs
        #pragma unroll
        for (int p = 0; p < 2; ++p) {
            short8 pf[2];
            #pragma unroll
            for (int qt = 0; qt < 2; ++qt)
                #pragma unroll
                for (int r = 0; r < 4; ++r) {
                    pf[qt][r]     = f2bs(st[qt][2 * p][r]);
                    pf[qt][4 + r] = f2bs(st[qt][2 * p + 1][r]);
                }
            #pragma unroll
            for (int mt = 0; mt < 4; ++mt) {
                const int vr = (mt * 16 + lm) * 66 + p * 32 + quad * 4;
                const short4v vlo = *(const short4v*)&Vt[vr];
                const short4v vhi = *(const short4v*)&Vt[vr + 16];
                short8 vf;
                vf[0] = vlo[0]; vf[1] = vlo[1]; vf[2] = vlo[2]; vf[3] = vlo[3];
                vf[4] = vhi[0]; vf[5] = vhi[1]; vf[6] = vhi[2]; vf[7] = vhi[3];
                #pragma unroll
                for (int qt = 0; qt < 2; ++qt)
                    oacc[qt][mt] = __builtin_amdgcn_mfma_f32_16x16x32_bf16(vf, pf[qt], oacc[qt][mt], 0, 0, 0);
            }
        }
        __syncthreads();
    }

    // rowsum: reduce across quads
    #pragma unroll
    for (int qt = 0; qt < 2; ++qt) {
        lsum[qt] += __shfl_xor(lsum[qt], 16, 64);
        lsum[qt] += __shfl_xor(lsum[qt], 32, 64);
    }

    // epilogue: s = x + O, LN1 partial stats
    float s1 = 0.f, s2 = 0.f;
    #pragma unroll
    for (int qt = 0; qt < 2; ++qt) {
        const float inv = 1.0f / lsum[qt];
        const size_t grow = rowb + qbase0 + qt * 16 + lm;
        #pragma unroll
        for (int mt = 0; mt < 4; ++mt) {
            const size_t base = grow * CD + hoff + mt * 16 + quad * 4;
            const float4 xv = *(const float4*)&x[base];
            const float xa[4] = {xv.x, xv.y, xv.z, xv.w};
            short4v sv;
            #pragma unroll
            for (int r = 0; r < 4; ++r) {
                const float s = xa[r] + oacc[qt][mt][r] * inv;
                s1 += s; s2 += s * s;
                sv[r] = f2bs(s);
            }
            *(short4v*)&sbuf[base] = sv;
        }
    }
    #pragma unroll
    for (int off = 1; off <= 32; off <<= 1) {
        s1 += __shfl_xor(s1, off, 64);
        s2 += __shfl_xor(s2, off, 64);
    }
    if (lane == 0) { red[wave] = s1; red[4 + wave] = s2; }
    __syncthreads();
    if (tid == 0) {
        atomicAdd(&stats[b * 2 + 0], red[0] + red[1] + red[2] + red[3]);
        atomicAdd(&stats[b * 2 + 1], red[4] + red[5] + red[6] + red[7]);
    }
}

// ---------------------------------------------------------------------------
// LN apply, vectorized 8 elems/thread: out = (s - mean) * rsqrt(var + eps)
// ---------------------------------------------------------------------------
template <typename TO>
__global__ void ln_apply(const short* __restrict__ s, const float* __restrict__ stats,
                         TO* __restrict__ out, int perBatch) {
    const int bId = blockIdx.y;
    const size_t base = (size_t)bId * perBatch;
    const float n = (float)perBatch;
    const float mean = stats[bId * 2 + 0] / n;
    const float var  = stats[bId * 2 + 1] / n - mean * mean + 1e-5f;
    const float inv  = rsqrtf(var);
    const int stride = gridDim.x * 256 * 8;
    for (int i = (blockIdx.x * 256 + threadIdx.x) * 8; i < perBatch; i += stride) {
        const short8 v8 = *(const short8*)&s[base + i];
        float o[8];
        #pragma unroll
        for (int j = 0; j < 8; ++j) o[j] = (bs2f(v8[j]) - mean) * inv;
        if (sizeof(TO) == 4) {
            float4 f0 = {o[0], o[1], o[2], o[3]}, f1 = {o[4], o[5], o[6], o[7]};
            *(float4*)&((float*)out)[base + i] = f0;
            *(float4*)&((float*)out)[base + i + 4] = f1;
        } else {
            short8 r;
            #pragma unroll
            for (int j = 0; j < 8; ++j) r[j] = f2bs(o[j]);
            *(short8*)&((short*)out)[base + i] = r;
        }
    }
}

// ---------------------------------------------------------------------------
extern "C" void kernel_launch(void* const* d_in, const int* in_sizes, int n_in,
                              void* d_out, int out_size, void* d_ws, size_t ws_size,
                              hipStream_t stream) {
    const float* x  = (const float*)d_in[0];
    const float* wq = (const float*)d_in[1];
    const float* bq = (const float*)d_in[2];
    const float* wk = (const float*)d_in[3];
    const float* bk = (const float*)d_in[4];
    const float* wv = (const float*)d_in[5];
    const float* bv = (const float*)d_in[6];
    const float* w1 = (const float*)d_in[7];
    const float* b1 = (const float*)d_in[8];
    const float* w2 = (const float*)d_in[9];
    const float* b2 = (const float*)d_in[10];

    const int BL = CB * CL;
    const int perBatch = CL * CD;

    // ws layout, 48MB + 64B:
    //   [0,8):   weights: Wqkvt(6MB)+bqkv -> w1t -> w2t
    //   [8,16):  xbf (dead after QKV gemm)
    //   [16,32): qk [4096][2048] (dead after attn)
    //   [32,40): vT [2][1024][2048] (dead after attn)
    //   [8,40):  ff1 (reuse)
    //   [40,48): sbuf/hbuf
    //   [48MB):  stats
    char* ws = (char*)d_ws;
    const size_t MB = 1024 * 1024;
    short* Wqkvt = (short*)(ws);
    float* bqkv  = (float*)(ws + 6 * MB);
    short* w1t   = (short*)(ws);
    short* w2t   = (short*)(ws);
    short* xbf   = (short*)(ws + 8 * MB);
    short* qkb   = (short*)(ws + 16 * MB);
    short* vT    = (short*)(ws + 32 * MB);
    short* ff1   = (short*)(ws + 8 * MB);
    short* hbuf  = (short*)(ws + 40 * MB);
    float* stats = (float*)(ws + 48 * MB);

    dim3 blk(256);

    pack_bias_kernel<<<12, blk, 0, stream>>>(bq, bk, bv, bqkv, stats);
    cvt_x_kernel<<<BL * CD / 1024, blk, 0, stream>>>(x, xbf);
    transpose_qkv<<<dim3(32, 32, 3), blk, 0, stream>>>(wq, wk, wv, Wqkvt);

    // fused QKV: xbf @ Wqkvt^T; q,k -> qkb[row][2048], v -> vT[b][dh][l]
    gemm_mfma<128, 0, 1><<<dim3(3072 / 128, BL / 128), blk, 0, stream>>>(
        xbf, Wqkvt, bqkv, qkb, vT, BL, 3072, CD, nullptr);

    // attention + residual + LN1 stats -> hbuf (s = x + attn)
    attn_mfma<<<dim3(CL / 128, NHEADS, CB), blk, 0, stream>>>(qkb, vT, x, hbuf, stats);

    // LN1 apply in-place
    ln_apply<bf16><<<dim3(128, CB), blk, 0, stream>>>(hbuf, stats, (bf16*)hbuf, perBatch);

    // FFN1
    transpose_cvt<<<dim3(128, 32), blk, 0, stream>>>(w1, w1t, CD, CH, 0);
    gemm_mfma<128, 1, 0><<<dim3(CH / 128, BL / 128), blk, 0, stream>>>(
        hbuf, w1t, b1, ff1, nullptr, BL, CH, CD, nullptr);

    // FFN2 + residual + LN2 stats (BN=64 -> 512 blocks)
    transpose_cvt<<<dim3(32, 128), blk, 0, stream>>>(w2, w2t, CH, CD, 0);
    gemm_mfma<64, 0, 2><<<dim3(CD / 64, BL / 128), blk, 0, stream>>>(
        ff1, w2t, b2, hbuf, nullptr, BL, CD, CH, stats + 8);

    // LN2 apply -> out fp32
    ln_apply<float><<<dim3(128, CB), blk, 0, stream>>>(hbuf, stats + 8, (float*)d_out, perBatch);
}

// Round 7
// 368.667 us; speedup vs baseline: 10.8221x; 1.0520x over previous
//
#include <hip/hip_runtime.h>
#include <hip/hip_bf16.h>

typedef __hip_bfloat16 bf16;
typedef __attribute__((ext_vector_type(8))) short short8;
typedef __attribute__((ext_vector_type(4))) short short4v;
typedef __attribute__((ext_vector_type(4))) float f32x4;

#define CB 2
#define CL 2048
#define CD 1024
#define CH 4096
#define NHEADS 16
#define DH 64

__device__ __forceinline__ short f2bs(float f) {
    __hip_bfloat16 h = __float2bfloat16(f);
    return *reinterpret_cast<short*>(&h);
}
__device__ __forceinline__ float bs2f(short s) {
    __hip_bfloat16 h = *reinterpret_cast<__hip_bfloat16*>(&s);
    return __bfloat162float(h);
}

__device__ __forceinline__ void async_copy16(const short* g, short* l) {
    __builtin_amdgcn_global_load_lds((const __attribute__((address_space(1))) unsigned int*)g,
                                     (__attribute__((address_space(3))) unsigned int*)l,
                                     16, 0, 0);
}

// pack QKV bias + zero LN stats (one launch)
__global__ void pack_bias_kernel(const float* __restrict__ bq, const float* __restrict__ bk,
                                 const float* __restrict__ bv, float* __restrict__ o,
                                 float* __restrict__ stats) {
    int i = blockIdx.x * 256 + threadIdx.x;
    if (i < 16) stats[i] = 0.0f;
    if (i < 3072) o[i] = i < 1024 ? bq[i] : (i < 2048 ? bk[i - 1024] : bv[i - 2048]);
}

// x fp32 -> bf16, 4 elems/thread
__global__ void cvt_x_kernel(const float* __restrict__ x, short* __restrict__ o) {
    const int i = (blockIdx.x * 256 + threadIdx.x) * 4;
    const float4 v = *(const float4*)&x[i];
    short4v s; s[0] = f2bs(v.x); s[1] = f2bs(v.y); s[2] = f2bs(v.z); s[3] = f2bs(v.w);
    *(short4v*)&o[i] = s;
}

// in[K][N] f32 -> out[row_off + n][k] bf16 (out row stride = K)
__global__ void transpose_cvt(const float* __restrict__ in, short* __restrict__ out,
                              int K, int N, int row_off) {
    __shared__ float T[32][33];
    const int tx = threadIdx.x & 31, ty = threadIdx.x >> 5;
    const int k0 = blockIdx.y * 32, n0 = blockIdx.x * 32;
    #pragma unroll
    for (int i = 0; i < 4; ++i)
        T[ty + i * 8][tx] = in[(size_t)(k0 + ty + i * 8) * N + n0 + tx];
    __syncthreads();
    #pragma unroll
    for (int i = 0; i < 4; ++i)
        out[(size_t)(row_off + n0 + ty + i * 8) * K + k0 + tx] = f2bs(T[tx][ty + i * 8]);
}

// 3 QKV weight transposes in one launch (z selects source)
__global__ void transpose_qkv(const float* __restrict__ wq, const float* __restrict__ wk,
                              const float* __restrict__ wv, short* __restrict__ out) {
    __shared__ float T[32][33];
    const int z = blockIdx.z;
    const float* in = z == 0 ? wq : (z == 1 ? wk : wv);
    const int row_off = z * 1024;
    const int tx = threadIdx.x & 31, ty = threadIdx.x >> 5;
    const int k0 = blockIdx.y * 32, n0 = blockIdx.x * 32;
    #pragma unroll
    for (int i = 0; i < 4; ++i)
        T[ty + i * 8][tx] = in[(size_t)(k0 + ty + i * 8) * CD + n0 + tx];
    __syncthreads();
    #pragma unroll
    for (int i = 0; i < 4; ++i)
        out[(size_t)(row_off + n0 + ty + i * 8) * CD + k0 + tx] = f2bs(T[tx][ty + i * 8]);
}

// ---------------------------------------------------------------------------
// MFMA GEMM. BM=128, BN in {128,64}, BK=64 as two 32-K slabs in LDS, staged
// chunk-linearly (chunk c -> &As[c*8]) so global_load_lds contiguity and the
// m97 frag-read bank pattern both hold. Grid must be (N/BN, 32).
// XCD swizzle: linear id % 8 groups ~4 row-strips per XCD (perf heuristic).
// EPI 0: C = act(acc+bias)
// EPI 1: QKV split: col<2048 -> qk[row*2048+col]; col>=2048 -> vT[b][dh][l]
// EPI 2: LN2: v += C(hbuf); in-place write; atomicAdd (sum,sumsq) -> stats
// ---------------------------------------------------------------------------
template <int BN, int RELU, int EPI>
__launch_bounds__(256)
__global__ void gemm_mfma(const short* __restrict__ A,
                          const short* __restrict__ Bt,
                          const float* __restrict__ bias,
                          short* __restrict__ C,
                          short* __restrict__ C2,
                          int M, int N, int K,
                          float* __restrict__ stats) {
    constexpr int NT = BN / 32;
    __shared__ short As[2 * 128 * 32];       // slab s = chunks [s*512, s*512+512)
    __shared__ short Bs[2 * BN * 32];        // slab s = chunks [s*BN*4, ...)
    __shared__ float red[8];

    const int tid = threadIdx.x;
    const int wave = tid >> 6, lane = tid & 63, quad = lane >> 4, lm = lane & 15;
    const int wm = (wave & 1) * 64, wn = (wave >> 1) * (NT * 16);

    // XCD-aware swizzle (assumes gridDim.y == 32, hw xcd = linear id % 8)
    const int id = blockIdx.y * gridDim.x + blockIdx.x;
    const int xcd = id & 7, within = id >> 3;
    const int by = xcd * 4 + (within & 3);
    const int bx = within >> 2;
    const int row0 = by * 128, col0 = bx * BN;

    f32x4 acc[4][NT];
    #pragma unroll
    for (int i = 0; i < 4; ++i)
        #pragma unroll
        for (int j = 0; j < NT; ++j) { f32x4 z = {0.f, 0.f, 0.f, 0.f}; acc[i][j] = z; }

    for (int k0 = 0; k0 < K; k0 += 64) {
        // A: 1024 chunks (2 slabs x 512), chunk-linear
        #pragma unroll
        for (int t = 0; t < 4; ++t) {
            const int c = t * 256 + tid;
            const int slab = c >> 9, idx = c & 511;
            const int r = idx >> 2, seg = idx & 3;
            async_copy16(A + (size_t)(row0 + r) * K + k0 + slab * 32 + seg * 8, &As[c * 8]);
        }
        // B: BN*8 chunks (2 slabs x BN*4), chunk-linear
        #pragma unroll
        for (int t = 0; t < BN / 32; ++t) {
            const int c = t * 256 + tid;
            const int slab = c / (BN * 4), idx = c % (BN * 4);
            const int r = idx >> 2, seg = idx & 3;
            async_copy16(Bt + (size_t)(col0 + r) * K + k0 + slab * 32 + seg * 8, &Bs[c * 8]);
        }
        __syncthreads();

        #pragma unroll
        for (int kh = 0; kh < 2; ++kh) {
            short8 af[4], bfr[NT];
            #pragma unroll
            for (int mt = 0; mt < 4; ++mt)
                af[mt] = *(const short8*)&As[kh * 4096 + (wm + mt * 16 + lm) * 32 + quad * 8];
            #pragma unroll
            for (int nt = 0; nt < NT; ++nt)
                bfr[nt] = *(const short8*)&Bs[kh * (BN * 32) + (wn + nt * 16 + lm) * 32 + quad * 8];
            #pragma unroll
            for (int mt = 0; mt < 4; ++mt)
                #pragma unroll
                for (int nt = 0; nt < NT; ++nt)
                    acc[mt][nt] = __builtin_amdgcn_mfma_f32_16x16x32_bf16(af[mt], bfr[nt], acc[mt][nt], 0, 0, 0);
        }
        __syncthreads();
    }

    float s1 = 0.f, s2 = 0.f;
    #pragma unroll
    for (int mt = 0; mt < 4; ++mt) {
        #pragma unroll
        for (int nt = 0; nt < NT; ++nt) {
            const int col = col0 + wn + nt * 16 + lm;
            const float bv = bias[col];
            const int rowb = row0 + wm + mt * 16 + quad * 4;
            if (EPI == 1 && col >= 2048) {
                const int b = row0 >> 11;
                const int l0 = rowb & (CL - 1);
                short4v sv;
                #pragma unroll
                for (int r = 0; r < 4; ++r) sv[r] = f2bs(acc[mt][nt][r] + bv);
                *(short4v*)&C2[(size_t)b * CD * CL + (size_t)(col - 2048) * CL + l0] = sv;
            } else {
                #pragma unroll
                for (int r = 0; r < 4; ++r) {
                    float v = acc[mt][nt][r] + bv;
                    if (RELU) v = fmaxf(v, 0.f);
                    const int ld = (EPI == 1) ? 2048 : N;
                    const size_t idx = (size_t)(rowb + r) * ld + col;
                    if (EPI == 2) {
                        v += bs2f(C[idx]);
                        s1 += v; s2 += v * v;
                    }
                    C[idx] = f2bs(v);
                }
            }
        }
    }
    if (EPI == 2) {
        #pragma unroll
        for (int off = 1; off <= 32; off <<= 1) {
            s1 += __shfl_xor(s1, off, 64);
            s2 += __shfl_xor(s2, off, 64);
        }
        if (lane == 0) { red[wave] = s1; red[4 + wave] = s2; }
        __syncthreads();
        if (tid == 0) {
            const int batch = row0 >> 11;
            atomicAdd(&stats[batch * 2 + 0], red[0] + red[1] + red[2] + red[3]);
            atomicAdd(&stats[batch * 2 + 1], red[4] + red[5] + red[6] + red[7]);
        }
    }
}

// ---------------------------------------------------------------------------
// Attention, S^T formulation, KT=64 keys/iter, dense PV.
// XCD swizzle: all 16 q-blocks of one (b,h) on one XCD (K/V L2 locality).
// ---------------------------------------------------------------------------
__launch_bounds__(256)
__global__ void attn_mfma(const short* __restrict__ qk,
                          const short* __restrict__ vT,
                          const float* __restrict__ x,
                          short* __restrict__ sbuf,
                          float* __restrict__ stats) {
    __shared__ short Ks[64 * 64];       // [key64][dh64]      8 KB
    __shared__ short Vt[64 * 66];       // [dh64][key64 +2]   8.25 KB
    __shared__ float red[8];

    const int tid = threadIdx.x;
    const int wave = tid >> 6, lane = tid & 63, quad = lane >> 4, lm = lane & 15;

    const int id = blockIdx.z * (16 * 16) + blockIdx.y * 16 + blockIdx.x;
    const int xcd = id & 7, rest = id >> 3;
    const int qx = rest & 15, gq = rest >> 4;
    const int g = gq * 8 + xcd;
    const int h = g & 15, b = g >> 4;

    const int hoff = h * DH;
    const size_t rowb = (size_t)b * CL;
    const size_t vbase = (size_t)b * CD * CL + (size_t)hoff * CL;
    const int qbase0 = qx * 128 + wave * 32;

    short8 bq[2][2];
    #pragma unroll
    for (int qt = 0; qt < 2; ++qt)
        #pragma unroll
        for (int kf = 0; kf < 2; ++kf)
            bq[qt][kf] = *(const short8*)(qk + (rowb + qbase0 + qt * 16 + lm) * 2048 + hoff + kf * 32 + quad * 8);

    f32x4 oacc[2][4];
    #pragma unroll
    for (int qt = 0; qt < 2; ++qt)
        #pragma unroll
        for (int mt = 0; mt < 4; ++mt) { f32x4 z = {0.f, 0.f, 0.f, 0.f}; oacc[qt][mt] = z; }
    float lsum[2] = {0.f, 0.f};

    for (int kt = 0; kt < CL / 64; ++kt) {
        #pragma unroll
        for (int t = 0; t < 2; ++t) {
            const int c = tid + t * 256;
            const int key = c >> 3, seg = c & 7;
            async_copy16(qk + (rowb + kt * 64 + key) * 2048 + 1024 + hoff + seg * 8, &Ks[c * 8]);
        }
        #pragma unroll
        for (int t = 0; t < 2; ++t) {
            const int c = tid + t * 256;
            const int row = c >> 3, seg = c & 7;
            const short8 vv = *(const short8*)(vT + vbase + (size_t)row * CL + kt * 64 + seg * 8);
            *(short8*)&Vt[row * 66 + seg * 8] = vv;
        }
        __syncthreads();

        float st[2][4][4];
        #pragma unroll
        for (int ktile = 0; ktile < 4; ++ktile) {
            const short8 a0 = *(const short8*)&Ks[(ktile * 16 + lm) * 64 + quad * 8];
            const short8 a1 = *(const short8*)&Ks[(ktile * 16 + lm) * 64 + 32 + quad * 8];
            #pragma unroll
            for (int qt = 0; qt < 2; ++qt) {
                f32x4 s = {0.f, 0.f, 0.f, 0.f};
                s = __builtin_amdgcn_mfma_f32_16x16x32_bf16(a0, bq[qt][0], s, 0, 0, 0);
                s = __builtin_amdgcn_mfma_f32_16x16x32_bf16(a1, bq[qt][1], s, 0, 0, 0);
                #pragma unroll
                for (int r = 0; r < 4; ++r) {
                    const float p = __expf(s[r] * 0.125f);
                    lsum[qt] += p;
                    st[qt][ktile][r] = p;
                }
            }
        }

        #pragma unroll
        for (int p = 0; p < 2; ++p) {
            short8 pf[2];
            #pragma unroll
            for (int qt = 0; qt < 2; ++qt)
                #pragma unroll
                for (int r = 0; r < 4; ++r) {
                    pf[qt][r]     = f2bs(st[qt][2 * p][r]);
                    pf[qt][4 + r] = f2bs(st[qt][2 * p + 1][r]);
                }
            #pragma unroll
            for (int mt = 0; mt < 4; ++mt) {
                const int vr = (mt * 16 + lm) * 66 + p * 32 + quad * 4;
                const short4v vlo = *(const short4v*)&Vt[vr];
                const short4v vhi = *(const short4v*)&Vt[vr + 16];
                short8 vf;
                vf[0] = vlo[0]; vf[1] = vlo[1]; vf[2] = vlo[2]; vf[3] = vlo[3];
                vf[4] = vhi[0]; vf[5] = vhi[1]; vf[6] = vhi[2]; vf[7] = vhi[3];
                #pragma unroll
                for (int qt = 0; qt < 2; ++qt)
                    oacc[qt][mt] = __builtin_amdgcn_mfma_f32_16x16x32_bf16(vf, pf[qt], oacc[qt][mt], 0, 0, 0);
            }
        }
        __syncthreads();
    }

    #pragma unroll
    for (int qt = 0; qt < 2; ++qt) {
        lsum[qt] += __shfl_xor(lsum[qt], 16, 64);
        lsum[qt] += __shfl_xor(lsum[qt], 32, 64);
    }

    float s1 = 0.f, s2 = 0.f;
    #pragma unroll
    for (int qt = 0; qt < 2; ++qt) {
        const float inv = 1.0f / lsum[qt];
        const size_t grow = rowb + qbase0 + qt * 16 + lm;
        #pragma unroll
        for (int mt = 0; mt < 4; ++mt) {
            const size_t base = grow * CD + hoff + mt * 16 + quad * 4;
            const float4 xv = *(const float4*)&x[base];
            const float xa[4] = {xv.x, xv.y, xv.z, xv.w};
            short4v sv;
            #pragma unroll
            for (int r = 0; r < 4; ++r) {
                const float s = xa[r] + oacc[qt][mt][r] * inv;
                s1 += s; s2 += s * s;
                sv[r] = f2bs(s);
            }
            *(short4v*)&sbuf[base] = sv;
        }
    }
    #pragma unroll
    for (int off = 1; off <= 32; off <<= 1) {
        s1 += __shfl_xor(s1, off, 64);
        s2 += __shfl_xor(s2, off, 64);
    }
    if (lane == 0) { red[wave] = s1; red[4 + wave] = s2; }
    __syncthreads();
    if (tid == 0) {
        atomicAdd(&stats[b * 2 + 0], red[0] + red[1] + red[2] + red[3]);
        atomicAdd(&stats[b * 2 + 1], red[4] + red[5] + red[6] + red[7]);
    }
}

// ---------------------------------------------------------------------------
// LN apply, vectorized 8 elems/thread
// ---------------------------------------------------------------------------
template <typename TO>
__global__ void ln_apply(const short* __restrict__ s, const float* __restrict__ stats,
                         TO* __restrict__ out, int perBatch) {
    const int bId = blockIdx.y;
    const size_t base = (size_t)bId * perBatch;
    const float n = (float)perBatch;
    const float mean = stats[bId * 2 + 0] / n;
    const float var  = stats[bId * 2 + 1] / n - mean * mean + 1e-5f;
    const float inv  = rsqrtf(var);
    const int stride = gridDim.x * 256 * 8;
    for (int i = (blockIdx.x * 256 + threadIdx.x) * 8; i < perBatch; i += stride) {
        const short8 v8 = *(const short8*)&s[base + i];
        float o[8];
        #pragma unroll
        for (int j = 0; j < 8; ++j) o[j] = (bs2f(v8[j]) - mean) * inv;
        if (sizeof(TO) == 4) {
            float4 f0 = {o[0], o[1], o[2], o[3]}, f1 = {o[4], o[5], o[6], o[7]};
            *(float4*)&((float*)out)[base + i] = f0;
            *(float4*)&((float*)out)[base + i + 4] = f1;
        } else {
            short8 r;
            #pragma unroll
            for (int j = 0; j < 8; ++j) r[j] = f2bs(o[j]);
            *(short8*)&((short*)out)[base + i] = r;
        }
    }
}

// ---------------------------------------------------------------------------
extern "C" void kernel_launch(void* const* d_in, const int* in_sizes, int n_in,
                              void* d_out, int out_size, void* d_ws, size_t ws_size,
                              hipStream_t stream) {
    const float* x  = (const float*)d_in[0];
    const float* wq = (const float*)d_in[1];
    const float* bq = (const float*)d_in[2];
    const float* wk = (const float*)d_in[3];
    const float* bk = (const float*)d_in[4];
    const float* wv = (const float*)d_in[5];
    const float* bv = (const float*)d_in[6];
    const float* w1 = (const float*)d_in[7];
    const float* b1 = (const float*)d_in[8];
    const float* w2 = (const float*)d_in[9];
    const float* b2 = (const float*)d_in[10];

    const int BL = CB * CL;
    const int perBatch = CL * CD;

    // ws layout, 48MB + 64B:
    //   [0,8):   weights: Wqkvt(6MB)+bqkv -> w1t -> w2t
    //   [8,16):  xbf (dead after QKV gemm)
    //   [16,32): qk [4096][2048] (dead after attn)
    //   [32,40): vT [2][1024][2048] (dead after attn)
    //   [8,40):  ff1 (reuse)
    //   [40,48): sbuf/hbuf
    //   [48MB):  stats
    char* ws = (char*)d_ws;
    const size_t MB = 1024 * 1024;
    short* Wqkvt = (short*)(ws);
    float* bqkv  = (float*)(ws + 6 * MB);
    short* w1t   = (short*)(ws);
    short* w2t   = (short*)(ws);
    short* xbf   = (short*)(ws + 8 * MB);
    short* qkb   = (short*)(ws + 16 * MB);
    short* vT    = (short*)(ws + 32 * MB);
    short* ff1   = (short*)(ws + 8 * MB);
    short* hbuf  = (short*)(ws + 40 * MB);
    float* stats = (float*)(ws + 48 * MB);

    dim3 blk(256);

    pack_bias_kernel<<<12, blk, 0, stream>>>(bq, bk, bv, bqkv, stats);
    cvt_x_kernel<<<BL * CD / 1024, blk, 0, stream>>>(x, xbf);
    transpose_qkv<<<dim3(32, 32, 3), blk, 0, stream>>>(wq, wk, wv, Wqkvt);

    // fused QKV: xbf @ Wqkvt^T; q,k -> qkb[row][2048], v -> vT[b][dh][l]
    gemm_mfma<128, 0, 1><<<dim3(3072 / 128, BL / 128), blk, 0, stream>>>(
        xbf, Wqkvt, bqkv, qkb, vT, BL, 3072, CD, nullptr);

    // attention + residual + LN1 stats -> hbuf (s = x + attn)
    attn_mfma<<<dim3(CL / 128, NHEADS, CB), blk, 0, stream>>>(qkb, vT, x, hbuf, stats);

    // LN1 apply in-place
    ln_apply<bf16><<<dim3(128, CB), blk, 0, stream>>>(hbuf, stats, (bf16*)hbuf, perBatch);

    // FFN1
    transpose_cvt<<<dim3(128, 32), blk, 0, stream>>>(w1, w1t, CD, CH, 0);
    gemm_mfma<128, 1, 0><<<dim3(CH / 128, BL / 128), blk, 0, stream>>>(
        hbuf, w1t, b1, ff1, nullptr, BL, CH, CD, nullptr);

    // FFN2 + residual + LN2 stats
    transpose_cvt<<<dim3(32, 128), blk, 0, stream>>>(w2, w2t, CH, CD, 0);
    gemm_mfma<64, 0, 2><<<dim3(CD / 64, BL / 128), blk, 0, stream>>>(
        ff1, w2t, b2, hbuf, nullptr, BL, CD, CH, stats + 8);

    // LN2 apply -> out fp32
    ln_apply<float><<<dim3(128, CB), blk, 0, stream>>>(hbuf, stats + 8, (float*)d_out, perBatch);
}

// Round 10
// 354.103 us; speedup vs baseline: 11.2672x; 1.0411x over previous
//
#include <hip/hip_runtime.h>
#include <hip/hip_bf16.h>

typedef __hip_bfloat16 bf16;
typedef __attribute__((ext_vector_type(8))) short short8;
typedef __attribute__((ext_vector_type(4))) short short4v;
typedef __attribute__((ext_vector_type(4))) float f32x4;

#define CB 2
#define CL 2048
#define CD 1024
#define CH 4096
#define NHEADS 16
#define DH 64

__device__ __forceinline__ short f2bs(float f) {
    __hip_bfloat16 h = __float2bfloat16(f);
    return *reinterpret_cast<short*>(&h);
}
__device__ __forceinline__ float bs2f(short s) {
    __hip_bfloat16 h = *reinterpret_cast<__hip_bfloat16*>(&s);
    return __bfloat162float(h);
}

__device__ __forceinline__ void async_copy16(const short* g, short* l) {
    __builtin_amdgcn_global_load_lds((const __attribute__((address_space(1))) unsigned int*)g,
                                     (__attribute__((address_space(3))) unsigned int*)l,
                                     16, 0, 0);
}

// pack QKV bias + zero LN stats (one launch)
__global__ void pack_bias_kernel(const float* __restrict__ bq, const float* __restrict__ bk,
                                 const float* __restrict__ bv, float* __restrict__ o,
                                 float* __restrict__ stats) {
    int i = blockIdx.x * 256 + threadIdx.x;
    if (i < 16) stats[i] = 0.0f;
    if (i < 3072) o[i] = i < 1024 ? bq[i] : (i < 2048 ? bk[i - 1024] : bv[i - 2048]);
}

// x fp32 -> bf16, 4 elems/thread
__global__ void cvt_x_kernel(const float* __restrict__ x, short* __restrict__ o) {
    const int i = (blockIdx.x * 256 + threadIdx.x) * 4;
    const float4 v = *(const float4*)&x[i];
    short4v s; s[0] = f2bs(v.x); s[1] = f2bs(v.y); s[2] = f2bs(v.z); s[3] = f2bs(v.w);
    *(short4v*)&o[i] = s;
}

// in[K][N] f32 -> out[row_off + n][k] bf16 (out row stride = K)
__global__ void transpose_cvt(const float* __restrict__ in, short* __restrict__ out,
                              int K, int N, int row_off) {
    __shared__ float T[32][33];
    const int tx = threadIdx.x & 31, ty = threadIdx.x >> 5;
    const int k0 = blockIdx.y * 32, n0 = blockIdx.x * 32;
    #pragma unroll
    for (int i = 0; i < 4; ++i)
        T[ty + i * 8][tx] = in[(size_t)(k0 + ty + i * 8) * N + n0 + tx];
    __syncthreads();
    #pragma unroll
    for (int i = 0; i < 4; ++i)
        out[(size_t)(row_off + n0 + ty + i * 8) * K + k0 + tx] = f2bs(T[tx][ty + i * 8]);
}

// 3 QKV weight transposes in one launch (z selects source)
__global__ void transpose_qkv(const float* __restrict__ wq, const float* __restrict__ wk,
                              const float* __restrict__ wv, short* __restrict__ out) {
    __shared__ float T[32][33];
    const int z = blockIdx.z;
    const float* in = z == 0 ? wq : (z == 1 ? wk : wv);
    const int row_off = z * 1024;
    const int tx = threadIdx.x & 31, ty = threadIdx.x >> 5;
    const int k0 = blockIdx.y * 32, n0 = blockIdx.x * 32;
    #pragma unroll
    for (int i = 0; i < 4; ++i)
        T[ty + i * 8][tx] = in[(size_t)(k0 + ty + i * 8) * CD + n0 + tx];
    __syncthreads();
    #pragma unroll
    for (int i = 0; i < 4; ++i)
        out[(size_t)(row_off + n0 + ty + i * 8) * CD + k0 + tx] = f2bs(T[tx][ty + i * 8]);
}

// ---------------------------------------------------------------------------
// MFMA GEMM. BM=128, BN in {128,64}, BK in {64,128} as BK/32 32-K slabs in
// LDS, staged chunk-linearly (chunk c -> &As[c*8]) so global_load_lds
// contiguity and the m97 frag-read bank pattern both hold.
// Grid must be (N/BN, 32). XCD swizzle: linear id % 8 (perf heuristic).
// EPI 0: C = act(acc+bias)
// EPI 1: QKV split: col<2048 -> qk[row*2048+col]; col>=2048 -> vT[b][dh][l]
// EPI 2: LN2: v += C(hbuf); in-place write; atomicAdd (sum,sumsq) -> stats
// ---------------------------------------------------------------------------
template <int BN, int BK, int RELU, int EPI>
__launch_bounds__(256)
__global__ void gemm_mfma(const short* __restrict__ A,
                          const short* __restrict__ Bt,
                          const float* __restrict__ bias,
                          short* __restrict__ C,
                          short* __restrict__ C2,
                          int M, int N, int K,
                          float* __restrict__ stats) {
    constexpr int NT = BN / 32;
    constexpr int KH = BK / 32;              // slabs
    constexpr int ACH = 16 * BK;             // A chunks total
    constexpr int BCH = BN * BK / 8;         // B chunks total
    __shared__ short As[128 * BK];           // slab s = chunks [s*512, s*512+512)
    __shared__ short Bs[BN * BK];            // slab s = chunks [s*BN*4, ...)
    __shared__ float red[8];

    const int tid = threadIdx.x;
    const int wave = tid >> 6, lane = tid & 63, quad = lane >> 4, lm = lane & 15;
    const int wm = (wave & 1) * 64, wn = (wave >> 1) * (NT * 16);

    // XCD-aware swizzle (assumes gridDim.y == 32, hw xcd = linear id % 8)
    const int id = blockIdx.y * gridDim.x + blockIdx.x;
    const int xcd = id & 7, within = id >> 3;
    const int by = xcd * 4 + (within & 3);
    const int bx = within >> 2;
    const int row0 = by * 128, col0 = bx * BN;

    f32x4 acc[4][NT];
    #pragma unroll
    for (int i = 0; i < 4; ++i)
        #pragma unroll
        for (int j = 0; j < NT; ++j) { f32x4 z = {0.f, 0.f, 0.f, 0.f}; acc[i][j] = z; }

    for (int k0 = 0; k0 < K; k0 += BK) {
        // A: chunk-linear (slab = 512 chunks of 16B = 128 rows x 32 k)
        #pragma unroll
        for (int t = 0; t < ACH / 256; ++t) {
            const int c = t * 256 + tid;
            const int slab = c >> 9, idx = c & 511;
            const int r = idx >> 2, seg = idx & 3;
            async_copy16(A + (size_t)(row0 + r) * K + k0 + slab * 32 + seg * 8, &As[c * 8]);
        }
        // B: chunk-linear (slab = BN*4 chunks)
        #pragma unroll
        for (int t = 0; t < BCH / 256; ++t) {
            const int c = t * 256 + tid;
            const int slab = c / (BN * 4), idx = c % (BN * 4);
            const int r = idx >> 2, seg = idx & 3;
            async_copy16(Bt + (size_t)(col0 + r) * K + k0 + slab * 32 + seg * 8, &Bs[c * 8]);
        }
        __syncthreads();

        #pragma unroll
        for (int kh = 0; kh < KH; ++kh) {
            short8 af[4], bfr[NT];
            #pragma unroll
            for (int mt = 0; mt < 4; ++mt)
                af[mt] = *(const short8*)&As[kh * 4096 + (wm + mt * 16 + lm) * 32 + quad * 8];
            #pragma unroll
            for (int nt = 0; nt < NT; ++nt)
                bfr[nt] = *(const short8*)&Bs[kh * (BN * 32) + (wn + nt * 16 + lm) * 32 + quad * 8];
            #pragma unroll
            for (int mt = 0; mt < 4; ++mt)
                #pragma unroll
                for (int nt = 0; nt < NT; ++nt)
                    acc[mt][nt] = __builtin_amdgcn_mfma_f32_16x16x32_bf16(af[mt], bfr[nt], acc[mt][nt], 0, 0, 0);
        }
        __syncthreads();
    }

    float s1 = 0.f, s2 = 0.f;
    #pragma unroll
    for (int mt = 0; mt < 4; ++mt) {
        #pragma unroll
        for (int nt = 0; nt < NT; ++nt) {
            const int col = col0 + wn + nt * 16 + lm;
            const float bv = bias[col];
            const int rowb = row0 + wm + mt * 16 + quad * 4;
            if (EPI == 1 && col >= 2048) {
                const int b = row0 >> 11;
                const int l0 = rowb & (CL - 1);
                short4v sv;
                #pragma unroll
                for (int r = 0; r < 4; ++r) sv[r] = f2bs(acc[mt][nt][r] + bv);
                *(short4v*)&C2[(size_t)b * CD * CL + (size_t)(col - 2048) * CL + l0] = sv;
            } else {
                #pragma unroll
                for (int r = 0; r < 4; ++r) {
                    float v = acc[mt][nt][r] + bv;
                    if (RELU) v = fmaxf(v, 0.f);
                    const int ld = (EPI == 1) ? 2048 : N;
                    const size_t idx = (size_t)(rowb + r) * ld + col;
                    if (EPI == 2) {
                        v += bs2f(C[idx]);
                        s1 += v; s2 += v * v;
                    }
                    C[idx] = f2bs(v);
                }
            }
        }
    }
    if (EPI == 2) {
        #pragma unroll
        for (int off = 1; off <= 32; off <<= 1) {
            s1 += __shfl_xor(s1, off, 64);
            s2 += __shfl_xor(s2, off, 64);
        }
        if (lane == 0) { red[wave] = s1; red[4 + wave] = s2; }
        __syncthreads();
        if (tid == 0) {
            const int batch = row0 >> 11;
            atomicAdd(&stats[batch * 2 + 0], red[0] + red[1] + red[2] + red[3]);
            atomicAdd(&stats[batch * 2 + 1], red[4] + red[5] + red[6] + red[7]);
        }
    }
}

// ---------------------------------------------------------------------------
// Attention, S^T formulation, KT=64 keys/iter, dense PV (R7-verified body).
// XCD swizzle: all 16 q-blocks of one (b,h) on one XCD (K/V L2 locality).
// ---------------------------------------------------------------------------
__launch_bounds__(256)
__global__ void attn_mfma(const short* __restrict__ qk,
                          const short* __restrict__ vT,
                          const float* __restrict__ x,
                          short* __restrict__ sbuf,
                          float* __restrict__ stats) {
    __shared__ short Ks[64 * 64];       // [key64][dh64]      8 KB
    __shared__ short Vt[64 * 66];       // [dh64][key64 +2]   8.25 KB
    __shared__ float red[8];

    const int tid = threadIdx.x;
    const int wave = tid >> 6, lane = tid & 63, quad = lane >> 4, lm = lane & 15;

    const int id = blockIdx.z * (16 * 16) + blockIdx.y * 16 + blockIdx.x;
    const int xcd = id & 7, rest = id >> 3;
    const int qx = rest & 15, gq = rest >> 4;
    const int g = gq * 8 + xcd;
    const int h = g & 15, b = g >> 4;

    const int hoff = h * DH;
    const size_t rowb = (size_t)b * CL;
    const size_t vbase = (size_t)b * CD * CL + (size_t)hoff * CL;
    const int qbase0 = qx * 128 + wave * 32;

    short8 bq[2][2];
    #pragma unroll
    for (int qt = 0; qt < 2; ++qt)
        #pragma unroll
        for (int kf = 0; kf < 2; ++kf)
            bq[qt][kf] = *(const short8*)(qk + (rowb + qbase0 + qt * 16 + lm) * 2048 + hoff + kf * 32 + quad * 8);

    f32x4 oacc[2][4];
    #pragma unroll
    for (int qt = 0; qt < 2; ++qt)
        #pragma unroll
        for (int mt = 0; mt < 4; ++mt) { f32x4 z = {0.f, 0.f, 0.f, 0.f}; oacc[qt][mt] = z; }
    float lsum[2] = {0.f, 0.f};

    for (int kt = 0; kt < CL / 64; ++kt) {
        #pragma unroll
        for (int t = 0; t < 2; ++t) {
            const int c = tid + t * 256;
            const int key = c >> 3, seg = c & 7;
            async_copy16(qk + (rowb + kt * 64 + key) * 2048 + 1024 + hoff + seg * 8, &Ks[c * 8]);
        }
        #pragma unroll
        for (int t = 0; t < 2; ++t) {
            const int c = tid + t * 256;
            const int row = c >> 3, seg = c & 7;
            const short8 vv = *(const short8*)(vT + vbase + (size_t)row * CL + kt * 64 + seg * 8);
            *(short8*)&Vt[row * 66 + seg * 8] = vv;
        }
        __syncthreads();

        float st[2][4][4];
        #pragma unroll
        for (int ktile = 0; ktile < 4; ++ktile) {
            const short8 a0 = *(const short8*)&Ks[(ktile * 16 + lm) * 64 + quad * 8];
            const short8 a1 = *(const short8*)&Ks[(ktile * 16 + lm) * 64 + 32 + quad * 8];
            #pragma unroll
            for (int qt = 0; qt < 2; ++qt) {
                f32x4 s = {0.f, 0.f, 0.f, 0.f};
                s = __builtin_amdgcn_mfma_f32_16x16x32_bf16(a0, bq[qt][0], s, 0, 0, 0);
                s = __builtin_amdgcn_mfma_f32_16x16x32_bf16(a1, bq[qt][1], s, 0, 0, 0);
                #pragma unroll
                for (int r = 0; r < 4; ++r) {
                    const float p = __expf(s[r] * 0.125f);
                    lsum[qt] += p;
                    st[qt][ktile][r] = p;
                }
            }
        }

        #pragma unroll
        for (int p = 0; p < 2; ++p) {
            short8 pf[2];
            #pragma unroll
            for (int qt = 0; qt < 2; ++qt)
                #pragma unroll
                for (int r = 0; r < 4; ++r) {
                    pf[qt][r]     = f2bs(st[qt][2 * p][r]);
                    pf[qt][4 + r] = f2bs(st[qt][2 * p + 1][r]);
                }
            #pragma unroll
            for (int mt = 0; mt < 4; ++mt) {
                const int vr = (mt * 16 + lm) * 66 + p * 32 + quad * 4;
                const short4v vlo = *(const short4v*)&Vt[vr];
                const short4v vhi = *(const short4v*)&Vt[vr + 16];
                short8 vf;
                vf[0] = vlo[0]; vf[1] = vlo[1]; vf[2] = vlo[2]; vf[3] = vlo[3];
                vf[4] = vhi[0]; vf[5] = vhi[1]; vf[6] = vhi[2]; vf[7] = vhi[3];
                #pragma unroll
                for (int qt = 0; qt < 2; ++qt)
                    oacc[qt][mt] = __builtin_amdgcn_mfma_f32_16x16x32_bf16(vf, pf[qt], oacc[qt][mt], 0, 0, 0);
            }
        }
        __syncthreads();
    }

    #pragma unroll
    for (int qt = 0; qt < 2; ++qt) {
        lsum[qt] += __shfl_xor(lsum[qt], 16, 64);
        lsum[qt] += __shfl_xor(lsum[qt], 32, 64);
    }

    float s1 = 0.f, s2 = 0.f;
    #pragma unroll
    for (int qt = 0; qt < 2; ++qt) {
        const float inv = 1.0f / lsum[qt];
        const size_t grow = rowb + qbase0 + qt * 16 + lm;
        #pragma unroll
        for (int mt = 0; mt < 4; ++mt) {
            const size_t base = grow * CD + hoff + mt * 16 + quad * 4;
            const float4 xv = *(const float4*)&x[base];
            const float xa[4] = {xv.x, xv.y, xv.z, xv.w};
            short4v sv;
            #pragma unroll
            for (int r = 0; r < 4; ++r) {
                const float s = xa[r] + oacc[qt][mt][r] * inv;
                s1 += s; s2 += s * s;
                sv[r] = f2bs(s);
            }
            *(short4v*)&sbuf[base] = sv;
        }
    }
    #pragma unroll
    for (int off = 1; off <= 32; off <<= 1) {
        s1 += __shfl_xor(s1, off, 64);
        s2 += __shfl_xor(s2, off, 64);
    }
    if (lane == 0) { red[wave] = s1; red[4 + wave] = s2; }
    __syncthreads();
    if (tid == 0) {
        atomicAdd(&stats[b * 2 + 0], red[0] + red[1] + red[2] + red[3]);
        atomicAdd(&stats[b * 2 + 1], red[4] + red[5] + red[6] + red[7]);
    }
}

// ---------------------------------------------------------------------------
// LN apply, vectorized 8 elems/thread
// ---------------------------------------------------------------------------
template <typename TO>
__global__ void ln_apply(const short* __restrict__ s, const float* __restrict__ stats,
                         TO* __restrict__ out, int perBatch) {
    const int bId = blockIdx.y;
    const size_t base = (size_t)bId * perBatch;
    const float n = (float)perBatch;
    const float mean = stats[bId * 2 + 0] / n;
    const float var  = stats[bId * 2 + 1] / n - mean * mean + 1e-5f;
    const float inv  = rsqrtf(var);
    const int stride = gridDim.x * 256 * 8;
    for (int i = (blockIdx.x * 256 + threadIdx.x) * 8; i < perBatch; i += stride) {
        const short8 v8 = *(const short8*)&s[base + i];
        float o[8];
        #pragma unroll
        for (int j = 0; j < 8; ++j) o[j] = (bs2f(v8[j]) - mean) * inv;
        if (sizeof(TO) == 4) {
            float4 f0 = {o[0], o[1], o[2], o[3]}, f1 = {o[4], o[5], o[6], o[7]};
            *(float4*)&((float*)out)[base + i] = f0;
            *(float4*)&((float*)out)[base + i + 4] = f1;
        } else {
            short8 r;
            #pragma unroll
            for (int j = 0; j < 8; ++j) r[j] = f2bs(o[j]);
            *(short8*)&((short*)out)[base + i] = r;
        }
    }
}

// ---------------------------------------------------------------------------
extern "C" void kernel_launch(void* const* d_in, const int* in_sizes, int n_in,
                              void* d_out, int out_size, void* d_ws, size_t ws_size,
                              hipStream_t stream) {
    const float* x  = (const float*)d_in[0];
    const float* wq = (const float*)d_in[1];
    const float* bq = (const float*)d_in[2];
    const float* wk = (const float*)d_in[3];
    const float* bk = (const float*)d_in[4];
    const float* wv = (const float*)d_in[5];
    const float* bv = (const float*)d_in[6];
    const float* w1 = (const float*)d_in[7];
    const float* b1 = (const float*)d_in[8];
    const float* w2 = (const float*)d_in[9];
    const float* b2 = (const float*)d_in[10];

    const int BL = CB * CL;
    const int perBatch = CL * CD;

    // ws layout, 48MB + 64B:
    //   [0,8):   weights: Wqkvt(6MB)+bqkv -> w1t -> w2t
    //   [8,16):  xbf (dead after QKV gemm)
    //   [16,32): qk [4096][2048] (dead after attn)
    //   [32,40): vT [2][1024][2048] (dead after attn)
    //   [8,40):  ff1 (reuse)
    //   [40,48): sbuf/hbuf
    //   [48MB):  stats
    char* ws = (char*)d_ws;
    const size_t MB = 1024 * 1024;
    short* Wqkvt = (short*)(ws);
    float* bqkv  = (float*)(ws + 6 * MB);
    short* w1t   = (short*)(ws);
    short* w2t   = (short*)(ws);
    short* xbf   = (short*)(ws + 8 * MB);
    short* qkb   = (short*)(ws + 16 * MB);
    short* vT    = (short*)(ws + 32 * MB);
    short* ff1   = (short*)(ws + 8 * MB);
    short* hbuf  = (short*)(ws + 40 * MB);
    float* stats = (float*)(ws + 48 * MB);

    dim3 blk(256);

    pack_bias_kernel<<<12, blk, 0, stream>>>(bq, bk, bv, bqkv, stats);
    cvt_x_kernel<<<BL * CD / 1024, blk, 0, stream>>>(x, xbf);
    transpose_qkv<<<dim3(32, 32, 3), blk, 0, stream>>>(wq, wk, wv, Wqkvt);

    // fused QKV: xbf @ Wqkvt^T; q,k -> qkb[row][2048], v -> vT[b][dh][l]
    gemm_mfma<128, 64, 0, 1><<<dim3(3072 / 128, BL / 128), blk, 0, stream>>>(
        xbf, Wqkvt, bqkv, qkb, vT, BL, 3072, CD, nullptr);

    // attention + residual + LN1 stats -> hbuf (s = x + attn)
    attn_mfma<<<dim3(CL / 128, NHEADS, CB), blk, 0, stream>>>(qkb, vT, x, hbuf, stats);

    // LN1 apply in-place
    ln_apply<bf16><<<dim3(128, CB), blk, 0, stream>>>(hbuf, stats, (bf16*)hbuf, perBatch);

    // FFN1
    transpose_cvt<<<dim3(128, 32), blk, 0, stream>>>(w1, w1t, CD, CH, 0);
    gemm_mfma<128, 64, 1, 0><<<dim3(CH / 128, BL / 128), blk, 0, stream>>>(
        hbuf, w1t, b1, ff1, nullptr, BL, CH, CD, nullptr);

    // FFN2 + residual + LN2 stats (BN=64, BK=128: 32 K-iters)
    transpose_cvt<<<dim3(32, 128), blk, 0, stream>>>(w2, w2t, CH, CD, 0);
    gemm_mfma<64, 128, 0, 2><<<dim3(CD / 64, BL / 128), blk, 0, stream>>>(
        ff1, w2t, b2, hbuf, nullptr, BL, CD, CH, stats + 8);

    // LN2 apply -> out fp32
    ln_apply<float><<<dim3(128, CB), blk, 0, stream>>>(hbuf, stats + 8, (float*)d_out, perBatch);
}